// Round 8
// baseline (230.485 us; speedup 1.0000x reference)
//
#include <hip/hip_runtime.h>
#include <hip/hip_bf16.h>
#include <math.h>

// Problem constants (B, S, E, D) for SA_Layer_45603962749650
#define Bb 8
#define Ss 2048
#define Ee 512
#define Dd 512
#define QSPLIT 16   // one partial per 128-row scores tile

typedef __bf16 bf16x8 __attribute__((ext_vector_type(8)));
typedef __bf16 bf16x4 __attribute__((ext_vector_type(4)));
typedef float f32x4 __attribute__((ext_vector_type(4)));

// ---------------------------------------------------------------------------
// Column softmax via fixed global shift:
//   P[q,k]   = exp(s[q,k]*scale - SHIFT)          (s >= 0 since q,k = relu(..))
//   l[k]     = sum_q P[q,k]
//   out[q,e] = x[q,e] + sum_k P[q,k] * (x[k,e]/l[k])
// Normalizer indexes the CONTRACTION axis k -> folds into x (XC): PV is a pure
// NT GEMM.
//
// R7 post-mortem: swizzle fix landed (bank conflicts 4.19M -> 0) but time was
// flat — the conflict was off the critical path; scores sits at the 2-phase
// structural ceiling (675 TF ~ m230's 682). R8: clone the verified BK=32
// 2-phase structure onto proj (was 64KB/2 blocks/CU) and pv (was 48KB/3
// blocks/CU -> now 24KB, grid-limited 4 blocks/CU). Accumulation order
// unchanged -> numerics identical.
// ---------------------------------------------------------------------------

// ---------------------------------------------------------------------------
// BK=64 async staging: 128x64 tile (16 KB), 4-wave blocks, 4 loads/thread.
// (kept for reference / unused paths removed)
// ---------------------------------------------------------------------------

// BK=32 async staging: 128x32 tile (8 KB), 512 slots, 2 loads/thread.
// Row = 4 chunks of 16B. Swizzle: data chunk c at phys p = c ^ ((row>>1)&3).
// Read phys = quad ^ ((l16>>1)&3) -> per-cycle 8-lane groups hit bank-groups
// {0,4,1,5,2,6,3,7}: conflict-free (verified R7: SQ_LDS_BANK_CONFLICT = 0).
__device__ __forceinline__ void stage32(ushort* lds, const __bf16* gbase,
                                        int ldg, int wave, int lane) {
#pragma unroll
    for (int t = 0; t < 2; ++t) {
        const int slot = wave * 128 + t * 64 + lane;
        const int row  = slot >> 2;
        const int c    = (slot & 3) ^ ((row >> 1) & 3);
        __builtin_amdgcn_global_load_lds(
            (const __attribute__((address_space(1))) void*)(gbase + (size_t)row * ldg + c * 8),
            (__attribute__((address_space(3))) void*)(lds + (size_t)slot * 8),
            16, 0, 0);
    }
}

// Same swizzle, 64-row x 32-col tile (4 KB): 256 slots, 1 load/thread.
__device__ __forceinline__ void stage32h64(ushort* lds, const __bf16* gbase,
                                           int ldg, int wave, int lane) {
    const int slot = wave * 64 + lane;
    const int row  = slot >> 2;
    const int c    = (slot & 3) ^ ((row >> 1) & 3);
    __builtin_amdgcn_global_load_lds(
        (const __attribute__((address_space(1))) void*)(gbase + (size_t)row * ldg + c * 8),
        (__attribute__((address_space(3))) void*)(lds + (size_t)slot * 8),
        16, 0, 0);
}

// ---------------------------------------------------------------------------
// prep_x (vectorized): one pass over x. xb = bf16(x) [B,S,E], xT = bf16(x^T)
// [B,E,S]. 64x64 tiles, float4 global loads, bf16x4/bf16x8 vector stores,
// padded [64][65] f32 LDS transpose.
// ---------------------------------------------------------------------------
__global__ __launch_bounds__(256) void prep_x(const float* __restrict__ in,
                                              __bf16* __restrict__ xb,
                                              __bf16* __restrict__ xT) {
    __shared__ float tile[64][65];
    const int b  = blockIdx.z;
    const int e0 = blockIdx.x * 64;   // grid.x = 8
    const int s0 = blockIdx.y * 64;   // grid.y = 32
    const float* ip = in + (size_t)b * Ss * Ee;
    __bf16* xbp = xb + (size_t)b * Ss * Ee;
    __bf16* xTp = xT + (size_t)b * Ee * Ss;
    const int tid  = threadIdx.x;
    const int rrow = tid >> 4;        // 0..15
    const int c4   = (tid & 15) * 4;  // f32 column within tile
    #pragma unroll
    for (int it = 0; it < 4; ++it) {
        const int r = it * 16 + rrow;
        const float4 v = *(const float4*)&ip[(size_t)(s0 + r) * Ee + e0 + c4];
        bf16x4 h;
        h[0] = (__bf16)v.x; h[1] = (__bf16)v.y; h[2] = (__bf16)v.z; h[3] = (__bf16)v.w;
        *(bf16x4*)&xbp[(size_t)(s0 + r) * Ee + e0 + c4] = h;
        tile[r][c4 + 0] = v.x; tile[r][c4 + 1] = v.y;
        tile[r][c4 + 2] = v.z; tile[r][c4 + 3] = v.w;
    }
    __syncthreads();
    const int sc  = (tid & 7) * 8;    // s-chunk of 8
    const int erb = tid >> 3;         // 0..31
    #pragma unroll
    for (int it = 0; it < 2; ++it) {
        const int er = it * 32 + erb;
        bf16x8 o;
        #pragma unroll
        for (int t = 0; t < 8; ++t) o[t] = (__bf16)tile[sc + t][er];
        *(bf16x8*)&xTp[(size_t)(e0 + er) * Ss + s0 + sc] = o;
    }
}

// ---------------------------------------------------------------------------
// Transpose 512x512: f32 in -> bf16 out. blockIdx.z selects Wq/Wk.
// ---------------------------------------------------------------------------
__global__ void transpose_w(const float* __restrict__ Wq, const float* __restrict__ Wk,
                            __bf16* __restrict__ WqT, __bf16* __restrict__ WkT) {
    __shared__ float tile[32][33];
    const float* in = blockIdx.z ? Wk : Wq;
    __bf16* out = blockIdx.z ? WkT : WqT;
    const int x0 = blockIdx.x * 32;
    const int y0 = blockIdx.y * 32;
    for (int i = threadIdx.y; i < 32; i += 8)
        tile[i][threadIdx.x] = in[(size_t)(y0 + i) * 512 + (x0 + threadIdx.x)];
    __syncthreads();
    for (int i = threadIdx.y; i < 32; i += 8)
        out[(size_t)(x0 + i) * 512 + (y0 + threadIdx.x)] = (__bf16)tile[threadIdx.x][i];
}

// ---------------------------------------------------------------------------
// Projection GEMM (NT): Out = relu(X @ W + b).  128x128 tile, BK=32 dbuf
// (32 KB -> 4 blocks/CU, was 64 KB/2), 16 K-steps, 2-phase counted-vmcnt
// pipeline (scores-clone), swizzled epilogue store.
// ---------------------------------------------------------------------------
__global__ __launch_bounds__(256, 4) void proj_kernel(
    const __bf16* __restrict__ X,
    const __bf16* __restrict__ WqT, const __bf16* __restrict__ WkT,
    const float* __restrict__ bq, const float* __restrict__ bk,
    __bf16* __restrict__ qb, __bf16* __restrict__ kb)
{
    __shared__ __align__(16) ushort smem[4 * 128 * 32];   // As0|Bs0|As1|Bs1, 32 KB
    ushort* As0 = smem;
    ushort* Bs0 = smem + 4096;
    ushort* As1 = smem + 8192;
    ushort* Bs1 = smem + 12288;
    const __bf16* WT  = blockIdx.z ? WkT : WqT;
    const float* bias = blockIdx.z ? bk : bq;
    __bf16* Out       = blockIdx.z ? kb : qb;

    const int tid = threadIdx.x;
    const int wave = tid >> 6, lane = tid & 63, quad = lane >> 4, l16 = lane & 15;
    const int wm = (wave >> 1) * 64, wn = (wave & 1) * 64;
    const int m0 = blockIdx.y * 128, n0 = blockIdx.x * 128;
    const int K = 512;
    const int swk = (quad ^ ((l16 >> 1) & 3)) * 8;

    f32x4 acc[4][4];
    f32x4 zero = {0.f, 0.f, 0.f, 0.f};
    for (int i = 0; i < 4; i++) for (int j = 0; j < 4; j++) acc[i][j] = zero;

    stage32(As0, X  + (size_t)m0 * K, K, wave, lane);
    stage32(Bs0, WT + (size_t)n0 * K, K, wave, lane);
    #pragma unroll 2
    for (int t = 0; t < 16; ++t) {
        ushort* Ac = (t & 1) ? As1 : As0;
        ushort* Bc = (t & 1) ? Bs1 : Bs0;
        if (t < 15) {
            ushort* An = (t & 1) ? As0 : As1;
            ushort* Bn = (t & 1) ? Bs0 : Bs1;
            const int kn = (t + 1) * 32;
            stage32(An, X  + (size_t)m0 * K + kn, K, wave, lane);
            stage32(Bn, WT + (size_t)n0 * K + kn, K, wave, lane);
            asm volatile("s_waitcnt vmcnt(4)" ::: "memory");
        } else {
            asm volatile("s_waitcnt vmcnt(0)" ::: "memory");
        }
        __builtin_amdgcn_s_barrier();
        bf16x8 af[4], bfr[4];
        for (int i = 0; i < 4; i++) af[i]  = *(bf16x8*)&Ac[(wm + i * 16 + l16) * 32 + swk];
        for (int j = 0; j < 4; j++) bfr[j] = *(bf16x8*)&Bc[(wn + j * 16 + l16) * 32 + swk];
        for (int i = 0; i < 4; i++)
            for (int j = 0; j < 4; j++)
                acc[i][j] = __builtin_amdgcn_mfma_f32_16x16x32_bf16(af[i], bfr[j], acc[i][j], 0, 0, 0);
        __builtin_amdgcn_sched_barrier(0);
        __builtin_amdgcn_s_barrier();
    }

    // epilogue: bias+relu -> per-wave LDS patch (swizzled) -> coalesced stores
    ushort* patch = smem + wave * 4096;   // 64x64 bf16
    for (int j = 0; j < 4; j++) {
        const float bv = bias[n0 + wn + j * 16 + l16];
        const int colsw = (j * 16 + l16) ^ (quad * 16);
        for (int i = 0; i < 4; i++)
            for (int rr = 0; rr < 4; rr++) {
                float v = acc[i][j][rr] + bv;
                v = v > 0.f ? v : 0.f;
                patch[(i * 16 + quad * 4 + rr) * 64 + colsw] = ((ushort2*)&v)[0].y;
            }
    }
    __syncthreads();
    #pragma unroll
    for (int it = 0; it < 8; it++) {
        const int lr = it * 8 + (lane >> 3);
        const int lc = ((lane & 7) * 8) ^ (((lr >> 2) & 3) * 16);
        const bf16x8 v = *(const bf16x8*)&patch[lr * 64 + lc];
        *(bf16x8*)&Out[(size_t)(m0 + wm + lr) * 512 + n0 + wn + (((lane & 7) * 8))] = v;
    }
}

// ---------------------------------------------------------------------------
// Scores GEMM (NT), BK=32 dbuf (32 KB -> 4 blocks/CU), 16 K-steps, 2-phase
// counted-vmcnt pipeline, conflict-free swizzle (R7-verified).
// P = exp(s*scale - SHIFT) bf16 via swizzled LDS patch + column sums Lp.
// 1-D grid, XCD=batch swizzle.
// ---------------------------------------------------------------------------
__global__ __launch_bounds__(256, 4) void scores_kernel(
    const __bf16* __restrict__ Q,   // [B*S, D] bf16
    const __bf16* __restrict__ Km,  // [B*S, D] bf16
    __bf16* __restrict__ P,         // [B, S, S] bf16
    float* __restrict__ Lp)         // [QSPLIT, B, S] partial column sums
{
    __shared__ __align__(16) ushort smem[4 * 128 * 32];   // As0|Bs0|As1|Bs1, 32 KB
    __shared__ float stats[256];                          // Ls
    ushort* As0 = smem;
    ushort* Bs0 = smem + 4096;
    ushort* As1 = smem + 8192;
    ushort* Bs1 = smem + 12288;
    const int id = blockIdx.x;            // 0..2047
    const int b = id & 7;
    const int rest = id >> 3;             // 0..255
    const int qy = rest >> 4;             // q tile 0..15
    const int m0 = qy * 128;
    const int n0 = (rest & 15) * 128;     // k tile
    const __bf16* A  = Q  + (size_t)b * Ss * Dd;
    const __bf16* Bp = Km + (size_t)b * Ss * Dd;
    __bf16* C = P + (size_t)b * Ss * Ss;

    const int tid = threadIdx.x;
    const int wave = tid >> 6, lane = tid & 63, quad = lane >> 4, l16 = lane & 15;
    const int wm = (wave >> 1) * 64, wn = (wave & 1) * 64;
    const int swk = (quad ^ ((l16 >> 1) & 3)) * 8;
    const float scale = 0.044194173824159216f; // 1/sqrt(512)
    const float SHIFT = 8.0f;

    f32x4 acc[4][4];
    f32x4 zero = {0.f, 0.f, 0.f, 0.f};
    for (int i = 0; i < 4; i++) for (int j = 0; j < 4; j++) acc[i][j] = zero;

    stage32(As0, A  + (size_t)m0 * Dd, Dd, wave, lane);
    stage32(Bs0, Bp + (size_t)n0 * Dd, Dd, wave, lane);
    #pragma unroll 2
    for (int t = 0; t < 16; ++t) {
        ushort* Ac = (t & 1) ? As1 : As0;
        ushort* Bc = (t & 1) ? Bs1 : Bs0;
        if (t < 15) {
            ushort* An = (t & 1) ? As0 : As1;
            ushort* Bn = (t & 1) ? Bs0 : Bs1;
            const int kn = (t + 1) * 32;
            stage32(An, A  + (size_t)m0 * Dd + kn, Dd, wave, lane);
            stage32(Bn, Bp + (size_t)n0 * Dd + kn, Dd, wave, lane);
            asm volatile("s_waitcnt vmcnt(4)" ::: "memory");
        } else {
            asm volatile("s_waitcnt vmcnt(0)" ::: "memory");
        }
        __builtin_amdgcn_s_barrier();
        bf16x8 af[4], bfr[4];
        for (int i = 0; i < 4; i++) af[i]  = *(bf16x8*)&Ac[(wm + i * 16 + l16) * 32 + swk];
        for (int j = 0; j < 4; j++) bfr[j] = *(bf16x8*)&Bc[(wn + j * 16 + l16) * 32 + swk];
        for (int i = 0; i < 4; i++)
            for (int j = 0; j < 4; j++)
                acc[i][j] = __builtin_amdgcn_mfma_f32_16x16x32_bf16(af[i], bfr[j], acc[i][j], 0, 0, 0);
        __builtin_amdgcn_sched_barrier(0);
        __builtin_amdgcn_s_barrier();
    }

    // ---- exp -> per-wave LDS patch (swizzled, reuses smem) + column sums ----
    float* Ls = stats;                    // 256 f32
    const int half = wave >> 1;
    ushort* patch = smem + wave * 4096;   // 64x64 bf16
    float lj[4];
    for (int j = 0; j < 4; j++) {
        float l = 0.f;
        const int colsw = (j * 16 + l16) ^ (quad * 16);
        for (int i = 0; i < 4; i++)
            for (int rr = 0; rr < 4; rr++) {
                const float e = __expf(fmaf(acc[i][j][rr], scale, -SHIFT));
                const __bf16 pb = (__bf16)e;   // RNE
                patch[(i * 16 + quad * 4 + rr) * 64 + colsw] = *(const ushort*)&pb;
                l += e;
            }
        l += __shfl_xor(l, 16);
        l += __shfl_xor(l, 32);
        lj[j] = l;
    }
    if (quad == 0)
        for (int j = 0; j < 4; j++) Ls[half * 128 + wn + j * 16 + l16] = lj[j];
    __syncthreads();
    if (tid < 128) {
        const size_t o = ((size_t)qy * Bb + b) * Ss + n0 + tid;
        Lp[o] = Ls[tid] + Ls[128 + tid];
    }
    // ---- coalesced P store: 8 bf16x8 per thread ----
    #pragma unroll
    for (int it = 0; it < 8; it++) {
        const int lr = it * 8 + (lane >> 3);
        const int lc = ((lane & 7) * 8) ^ (((lr >> 2) & 3) * 16);
        const bf16x8 v = *(const bf16x8*)&patch[lr * 64 + lc];
        *(bf16x8*)&C[(size_t)(m0 + wm + lr) * Ss + n0 + wn + ((lane & 7) * 8)] = v;
    }
}

// ---------------------------------------------------------------------------
// Cinv[b][k] = 1 / sum_qy Lp[qy][b][k]
// ---------------------------------------------------------------------------
__global__ void stats_combine(const float* __restrict__ Lp, float* __restrict__ Cinv) {
    const int idx = blockIdx.x * 256 + threadIdx.x;  // over B*S columns
    float l = 0.f;
    for (int qy = 0; qy < QSPLIT; qy++) l += Lp[(size_t)qy * Bb * Ss + idx];
    Cinv[idx] = 1.0f / l;
}

// ---------------------------------------------------------------------------
// xscale: XC[b,e,k] = xT[b,e,k] * Cinv[b,k].  One block per (b,e) row.
// ---------------------------------------------------------------------------
__global__ void xscale_kernel(const __bf16* __restrict__ xT,
                              const float* __restrict__ Cinv,
                              __bf16* __restrict__ XC) {
    const int r = blockIdx.x;              // b*E + e  (4096 rows)
    const int b = r >> 9;                  // E = 512
    const size_t base = (size_t)r * Ss;
    const float* cp = Cinv + (size_t)b * Ss;
    const int k0 = threadIdx.x * 8;
    const bf16x8 v = *(const bf16x8*)&xT[base + k0];
    const float4 c0 = *(const float4*)&cp[k0];
    const float4 c1 = *(const float4*)&cp[k0 + 4];
    bf16x8 o;
    o[0] = (__bf16)((float)v[0] * c0.x);
    o[1] = (__bf16)((float)v[1] * c0.y);
    o[2] = (__bf16)((float)v[2] * c0.z);
    o[3] = (__bf16)((float)v[3] * c0.w);
    o[4] = (__bf16)((float)v[4] * c1.x);
    o[5] = (__bf16)((float)v[5] * c1.y);
    o[6] = (__bf16)((float)v[6] * c1.z);
    o[7] = (__bf16)((float)v[7] * c1.w);
    *(bf16x8*)&XC[base + k0] = o;
}

// ---------------------------------------------------------------------------
// PV GEMM (NT) — pure GEMM: Out = P @ XC + XB.  64x128 tile, 4 waves
// (wave tile 32x64), BK=32 dbuf (24 KB, grid-limited 4 blocks/CU, was 48 KB/3),
// 64 K-steps, 2-phase counted-vmcnt pipeline, conflict-free swizzle.
// ---------------------------------------------------------------------------
__global__ __launch_bounds__(256, 4) void pv_kernel(
    const __bf16* __restrict__ P,    // [B,S,S] bf16 shifted exp scores
    const __bf16* __restrict__ XC,   // [B,E,S] bf16 x^T pre-scaled by 1/l[k]
    const __bf16* __restrict__ XB,   // [B,S,E] bf16 (residual)
    float* __restrict__ Out)         // [B,S,E] f32
{
    __shared__ __align__(16) ushort smem[2 * (64 * 32 + 128 * 32)];  // 24 KB dbuf
    ushort* As0 = smem;                 // 64x32  (2048)
    ushort* Bs0 = smem + 2048;          // 128x32 (4096)
    ushort* As1 = smem + 6144;
    ushort* Bs1 = smem + 8192;
    const int id = blockIdx.x;            // 0..1023
    const int b = id & 7;
    const int rest = id >> 3;             // 0..127
    const int m0 = (rest >> 2) * 64;      // q tile (64 rows)
    const int n0 = (rest & 3) * 128;      // e tile
    const __bf16* A  = P  + (size_t)b * Ss * Ss;
    const __bf16* Bp = XC + (size_t)b * Ee * Ss;

    const int tid = threadIdx.x;
    const int wave = tid >> 6, lane = tid & 63, quad = lane >> 4, l16 = lane & 15;
    const int wm = (wave >> 1) * 32, wn = (wave & 1) * 64;
    const int swk = (quad ^ ((l16 >> 1) & 3)) * 8;

    f32x4 acc[2][4];
    f32x4 zero = {0.f, 0.f, 0.f, 0.f};
    for (int i = 0; i < 2; i++) for (int j = 0; j < 4; j++) acc[i][j] = zero;

    stage32h64(As0, A  + (size_t)m0 * Ss, Ss, wave, lane);
    stage32   (Bs0, Bp + (size_t)n0 * Ss, Ss, wave, lane);
    #pragma unroll 2
    for (int t = 0; t < 64; ++t) {
        ushort* Ac = (t & 1) ? As1 : As0;
        ushort* Bc = (t & 1) ? Bs1 : Bs0;
        if (t < 63) {
            ushort* An = (t & 1) ? As0 : As1;
            ushort* Bn = (t & 1) ? Bs0 : Bs1;
            const int kn = (t + 1) * 32;
            stage32h64(An, A  + (size_t)m0 * Ss + kn, Ss, wave, lane);
            stage32   (Bn, Bp + (size_t)n0 * Ss + kn, Ss, wave, lane);
            asm volatile("s_waitcnt vmcnt(3)" ::: "memory");
        } else {
            asm volatile("s_waitcnt vmcnt(0)" ::: "memory");
        }
        __builtin_amdgcn_s_barrier();
        bf16x8 af[2], bfr[4];
        for (int i = 0; i < 2; i++) af[i]  = *(bf16x8*)&Ac[(wm + i * 16 + l16) * 32 + swk];
        for (int j = 0; j < 4; j++) bfr[j] = *(bf16x8*)&Bc[(wn + j * 16 + l16) * 32 + swk];
        for (int i = 0; i < 2; i++)
            for (int j = 0; j < 4; j++)
                acc[i][j] = __builtin_amdgcn_mfma_f32_16x16x32_bf16(af[i], bfr[j], acc[i][j], 0, 0, 0);
        __builtin_amdgcn_sched_barrier(0);
        __builtin_amdgcn_s_barrier();
    }

    for (int i = 0; i < 2; i++) {
        for (int j = 0; j < 4; j++) {
            const int col = n0 + wn + j * 16 + l16;
            for (int rr = 0; rr < 4; rr++) {
                const int row = m0 + wm + i * 16 + quad * 4 + rr;
                const size_t idx = ((size_t)b * Ss + row) * Ee + col;
                Out[idx] = (float)XB[idx] + acc[i][j][rr];
            }
        }
    }
}

// ---------------------------------------------------------------------------
extern "C" void kernel_launch(void* const* d_in, const int* in_sizes, int n_in,
                              void* d_out, int out_size, void* d_ws, size_t ws_size,
                              hipStream_t stream) {
    const float* x  = (const float*)d_in[0];
    const float* Wq = (const float*)d_in[1];
    const float* bq = (const float*)d_in[2];
    const float* Wk = (const float*)d_in[3];
    const float* bk = (const float*)d_in[4];
    float* out = (float*)d_out;

    char* ws = (char*)d_ws;
    size_t off = 0;
    auto alloc = [&](size_t bytes) -> void* {
        void* p = ws + off;
        off += (bytes + 255) & ~(size_t)255;
        return p;
    };
    __bf16* P    = (__bf16*)alloc((size_t)Bb * Ss * Ss * 2);      // 64 MiB
    __bf16* xb   = (__bf16*)alloc((size_t)Bb * Ss * Ee * 2);
    __bf16* qb   = (__bf16*)alloc((size_t)Bb * Ss * Dd * 2);
    __bf16* kb   = (__bf16*)alloc((size_t)Bb * Ss * Dd * 2);
    __bf16* xT   = (__bf16*)alloc((size_t)Bb * Ee * Ss * 2);
    __bf16* WqT  = (__bf16*)alloc((size_t)512 * 512 * 2);
    __bf16* WkT  = (__bf16*)alloc((size_t)512 * 512 * 2);
    float*  Lp   = (float*)alloc((size_t)QSPLIT * Bb * Ss * 4);   // 1 MiB
    float*  Cinv = (float*)alloc((size_t)Bb * Ss * 4);            // 64 KiB
    if (off > ws_size) return;
    __bf16* XC = qb;   // reuse: qb is dead after scores_kernel (stream-ordered)

    prep_x<<<dim3(8, 32, 8), 256, 0, stream>>>(x, xb, xT);
    transpose_w<<<dim3(16, 16, 2), dim3(32, 8), 0, stream>>>(Wq, Wk, WqT, WkT);

    // q = relu(x Wq + bq), k = relu(x Wk + bk)
    proj_kernel<<<dim3(4, 128, 2), 256, 0, stream>>>(xb, WqT, WkT, bq, bk, qb, kb);

    // P = exp(q k^T / sqrt(E) - 8) bf16 + column-sum partials
    scores_kernel<<<dim3(2048), 256, 0, stream>>>(qb, kb, P, Lp);
    stats_combine<<<dim3(Bb * Ss / 256), 256, 0, stream>>>(Lp, Cinv);

    // XC = x^T / l[k]   (folds the softmax normalizer into the PV B-operand)
    xscale_kernel<<<dim3(Bb * Ee), 256, 0, stream>>>(xT, Cinv, XC);

    // out = x + P @ XC   (pure GEMM, residual fused)
    pv_kernel<<<dim3(1024), 256, 0, stream>>>(P, XC, xb, out);
}

// Round 9
// 210.553 us; speedup vs baseline: 1.0947x; 1.0947x over previous
//
#include <hip/hip_runtime.h>
#include <hip/hip_bf16.h>
#include <math.h>

// Problem constants (B, S, E, D) for SA_Layer_45603962749650
#define Bb 8
#define Ss 2048
#define Ee 512
#define Dd 512
#define QSPLIT 16   // one partial per 128-row scores tile

typedef __bf16 bf16x8 __attribute__((ext_vector_type(8)));
typedef __bf16 bf16x4 __attribute__((ext_vector_type(4)));
typedef float f32x4 __attribute__((ext_vector_type(4)));

// ---------------------------------------------------------------------------
// Column softmax via fixed global shift:
//   P[q,k]   = exp(s[q,k]*scale - SHIFT)          (s >= 0 since q,k = relu(..))
//   l[k]     = sum_q P[q,k]
//   out[q,e] = x[q,e] + sum_k P[q,k] * (x[k,e]/l[k])
// Normalizer indexes the CONTRACTION axis k -> folds into x (XC): PV is a pure
// NT GEMM.
//
// R8 post-mortem: pv at BK=32 regressed 51->67us. Cause: pv's wave tile is
// 32x64 -> only 8 MFMA per K-step vs ~100cyc fixed sync/stage cost per step,
// and step count doubled (MfmaUtil 30->20, FETCH +7GB). RULE: keep >=16 MFMA
// per barrier pair per wave; scores tolerates BK=32 (64x64 wave tile = 16).
// R9: pv reverted to the R7-proven BK=64/48KB 2-phase pipeline; proj keeps
// BK=32 (its isolated delta vs R7's 214.4us total is measured this round).
// ---------------------------------------------------------------------------

// ---------------------------------------------------------------------------
// BK=64 async staging: 128x64 tile (16 KB), 4-wave blocks, 4 loads/thread.
// Slot s (0..1023): row = s>>3, phys chunk = s&7, data chunk c = (s&7)^(row&7).
// LDS dest = wave-uniform base + lane*16 (m104-safe).
// ---------------------------------------------------------------------------
__device__ __forceinline__ void stage64(ushort* lds, const __bf16* gbase,
                                        int ldg, int wave, int lane) {
#pragma unroll
    for (int t = 0; t < 4; ++t) {
        const int slot = wave * 256 + t * 64 + lane;
        const int row  = slot >> 3;
        const int c    = (slot & 7) ^ (row & 7);
        __builtin_amdgcn_global_load_lds(
            (const __attribute__((address_space(1))) void*)(gbase + (size_t)row * ldg + c * 8),
            (__attribute__((address_space(3))) void*)(lds + (size_t)slot * 8),
            16, 0, 0);
    }
}

// Same layout, 64-row x 64-col tile (8 KB): 512 slots, 2 loads/thread.
__device__ __forceinline__ void stage64h(ushort* lds, const __bf16* gbase,
                                         int ldg, int wave, int lane) {
#pragma unroll
    for (int t = 0; t < 2; ++t) {
        const int slot = wave * 128 + t * 64 + lane;
        const int row  = slot >> 3;
        const int c    = (slot & 7) ^ (row & 7);
        __builtin_amdgcn_global_load_lds(
            (const __attribute__((address_space(1))) void*)(gbase + (size_t)row * ldg + c * 8),
            (__attribute__((address_space(3))) void*)(lds + (size_t)slot * 8),
            16, 0, 0);
    }
}

// BK=32 async staging: 128x32 tile (8 KB), 512 slots, 2 loads/thread.
// Swizzle: data chunk c at phys p = c ^ ((row>>1)&3); read phys =
// quad ^ ((l16>>1)&3) -> conflict-free (verified R7: SQ_LDS_BANK_CONFLICT = 0).
__device__ __forceinline__ void stage32(ushort* lds, const __bf16* gbase,
                                        int ldg, int wave, int lane) {
#pragma unroll
    for (int t = 0; t < 2; ++t) {
        const int slot = wave * 128 + t * 64 + lane;
        const int row  = slot >> 2;
        const int c    = (slot & 3) ^ ((row >> 1) & 3);
        __builtin_amdgcn_global_load_lds(
            (const __attribute__((address_space(1))) void*)(gbase + (size_t)row * ldg + c * 8),
            (__attribute__((address_space(3))) void*)(lds + (size_t)slot * 8),
            16, 0, 0);
    }
}

// ---------------------------------------------------------------------------
// prep_x (vectorized): one pass over x. xb = bf16(x) [B,S,E], xT = bf16(x^T)
// [B,E,S]. 64x64 tiles, float4 global loads, bf16x4/bf16x8 vector stores,
// padded [64][65] f32 LDS transpose.
// ---------------------------------------------------------------------------
__global__ __launch_bounds__(256) void prep_x(const float* __restrict__ in,
                                              __bf16* __restrict__ xb,
                                              __bf16* __restrict__ xT) {
    __shared__ float tile[64][65];
    const int b  = blockIdx.z;
    const int e0 = blockIdx.x * 64;   // grid.x = 8
    const int s0 = blockIdx.y * 64;   // grid.y = 32
    const float* ip = in + (size_t)b * Ss * Ee;
    __bf16* xbp = xb + (size_t)b * Ss * Ee;
    __bf16* xTp = xT + (size_t)b * Ee * Ss;
    const int tid  = threadIdx.x;
    const int rrow = tid >> 4;        // 0..15
    const int c4   = (tid & 15) * 4;  // f32 column within tile
    #pragma unroll
    for (int it = 0; it < 4; ++it) {
        const int r = it * 16 + rrow;
        const float4 v = *(const float4*)&ip[(size_t)(s0 + r) * Ee + e0 + c4];
        bf16x4 h;
        h[0] = (__bf16)v.x; h[1] = (__bf16)v.y; h[2] = (__bf16)v.z; h[3] = (__bf16)v.w;
        *(bf16x4*)&xbp[(size_t)(s0 + r) * Ee + e0 + c4] = h;
        tile[r][c4 + 0] = v.x; tile[r][c4 + 1] = v.y;
        tile[r][c4 + 2] = v.z; tile[r][c4 + 3] = v.w;
    }
    __syncthreads();
    const int sc  = (tid & 7) * 8;    // s-chunk of 8
    const int erb = tid >> 3;         // 0..31
    #pragma unroll
    for (int it = 0; it < 2; ++it) {
        const int er = it * 32 + erb;
        bf16x8 o;
        #pragma unroll
        for (int t = 0; t < 8; ++t) o[t] = (__bf16)tile[sc + t][er];
        *(bf16x8*)&xTp[(size_t)(e0 + er) * Ss + s0 + sc] = o;
    }
}

// ---------------------------------------------------------------------------
// Transpose 512x512: f32 in -> bf16 out. blockIdx.z selects Wq/Wk.
// ---------------------------------------------------------------------------
__global__ void transpose_w(const float* __restrict__ Wq, const float* __restrict__ Wk,
                            __bf16* __restrict__ WqT, __bf16* __restrict__ WkT) {
    __shared__ float tile[32][33];
    const float* in = blockIdx.z ? Wk : Wq;
    __bf16* out = blockIdx.z ? WkT : WqT;
    const int x0 = blockIdx.x * 32;
    const int y0 = blockIdx.y * 32;
    for (int i = threadIdx.y; i < 32; i += 8)
        tile[i][threadIdx.x] = in[(size_t)(y0 + i) * 512 + (x0 + threadIdx.x)];
    __syncthreads();
    for (int i = threadIdx.y; i < 32; i += 8)
        out[(size_t)(x0 + i) * 512 + (y0 + threadIdx.x)] = (__bf16)tile[threadIdx.x][i];
}

// ---------------------------------------------------------------------------
// Projection GEMM (NT): Out = relu(X @ W + b).  128x128 tile, BK=32 dbuf
// (32 KB -> 4 blocks/CU), 16 K-steps, 2-phase counted-vmcnt pipeline,
// swizzled epilogue store.  (Wave tile 64x64 = 16 MFMA/step: BK=32-safe.)
// ---------------------------------------------------------------------------
__global__ __launch_bounds__(256, 4) void proj_kernel(
    const __bf16* __restrict__ X,
    const __bf16* __restrict__ WqT, const __bf16* __restrict__ WkT,
    const float* __restrict__ bq, const float* __restrict__ bk,
    __bf16* __restrict__ qb, __bf16* __restrict__ kb)
{
    __shared__ __align__(16) ushort smem[4 * 128 * 32];   // As0|Bs0|As1|Bs1, 32 KB
    ushort* As0 = smem;
    ushort* Bs0 = smem + 4096;
    ushort* As1 = smem + 8192;
    ushort* Bs1 = smem + 12288;
    const __bf16* WT  = blockIdx.z ? WkT : WqT;
    const float* bias = blockIdx.z ? bk : bq;
    __bf16* Out       = blockIdx.z ? kb : qb;

    const int tid = threadIdx.x;
    const int wave = tid >> 6, lane = tid & 63, quad = lane >> 4, l16 = lane & 15;
    const int wm = (wave >> 1) * 64, wn = (wave & 1) * 64;
    const int m0 = blockIdx.y * 128, n0 = blockIdx.x * 128;
    const int K = 512;
    const int swk = (quad ^ ((l16 >> 1) & 3)) * 8;

    f32x4 acc[4][4];
    f32x4 zero = {0.f, 0.f, 0.f, 0.f};
    for (int i = 0; i < 4; i++) for (int j = 0; j < 4; j++) acc[i][j] = zero;

    stage32(As0, X  + (size_t)m0 * K, K, wave, lane);
    stage32(Bs0, WT + (size_t)n0 * K, K, wave, lane);
    #pragma unroll 2
    for (int t = 0; t < 16; ++t) {
        ushort* Ac = (t & 1) ? As1 : As0;
        ushort* Bc = (t & 1) ? Bs1 : Bs0;
        if (t < 15) {
            ushort* An = (t & 1) ? As0 : As1;
            ushort* Bn = (t & 1) ? Bs0 : Bs1;
            const int kn = (t + 1) * 32;
            stage32(An, X  + (size_t)m0 * K + kn, K, wave, lane);
            stage32(Bn, WT + (size_t)n0 * K + kn, K, wave, lane);
            asm volatile("s_waitcnt vmcnt(4)" ::: "memory");
        } else {
            asm volatile("s_waitcnt vmcnt(0)" ::: "memory");
        }
        __builtin_amdgcn_s_barrier();
        bf16x8 af[4], bfr[4];
        for (int i = 0; i < 4; i++) af[i]  = *(bf16x8*)&Ac[(wm + i * 16 + l16) * 32 + swk];
        for (int j = 0; j < 4; j++) bfr[j] = *(bf16x8*)&Bc[(wn + j * 16 + l16) * 32 + swk];
        for (int i = 0; i < 4; i++)
            for (int j = 0; j < 4; j++)
                acc[i][j] = __builtin_amdgcn_mfma_f32_16x16x32_bf16(af[i], bfr[j], acc[i][j], 0, 0, 0);
        __builtin_amdgcn_sched_barrier(0);
        __builtin_amdgcn_s_barrier();
    }

    // epilogue: bias+relu -> per-wave LDS patch (swizzled) -> coalesced stores
    ushort* patch = smem + wave * 4096;   // 64x64 bf16
    for (int j = 0; j < 4; j++) {
        const float bv = bias[n0 + wn + j * 16 + l16];
        const int colsw = (j * 16 + l16) ^ (quad * 16);
        for (int i = 0; i < 4; i++)
            for (int rr = 0; rr < 4; rr++) {
                float v = acc[i][j][rr] + bv;
                v = v > 0.f ? v : 0.f;
                patch[(i * 16 + quad * 4 + rr) * 64 + colsw] = ((ushort2*)&v)[0].y;
            }
    }
    __syncthreads();
    #pragma unroll
    for (int it = 0; it < 8; it++) {
        const int lr = it * 8 + (lane >> 3);
        const int lc = ((lane & 7) * 8) ^ (((lr >> 2) & 3) * 16);
        const bf16x8 v = *(const bf16x8*)&patch[lr * 64 + lc];
        *(bf16x8*)&Out[(size_t)(m0 + wm + lr) * 512 + n0 + wn + (((lane & 7) * 8))] = v;
    }
}

// ---------------------------------------------------------------------------
// Scores GEMM (NT), BK=32 dbuf (32 KB -> 4 blocks/CU), 16 K-steps, 2-phase
// counted-vmcnt pipeline, conflict-free swizzle (R7-verified).
// P = exp(s*scale - SHIFT) bf16 via swizzled LDS patch + column sums Lp.
// 1-D grid, XCD=batch swizzle.
// ---------------------------------------------------------------------------
__global__ __launch_bounds__(256, 4) void scores_kernel(
    const __bf16* __restrict__ Q,   // [B*S, D] bf16
    const __bf16* __restrict__ Km,  // [B*S, D] bf16
    __bf16* __restrict__ P,         // [B, S, S] bf16
    float* __restrict__ Lp)         // [QSPLIT, B, S] partial column sums
{
    __shared__ __align__(16) ushort smem[4 * 128 * 32];   // As0|Bs0|As1|Bs1, 32 KB
    __shared__ float stats[256];                          // Ls
    ushort* As0 = smem;
    ushort* Bs0 = smem + 4096;
    ushort* As1 = smem + 8192;
    ushort* Bs1 = smem + 12288;
    const int id = blockIdx.x;            // 0..2047
    const int b = id & 7;
    const int rest = id >> 3;             // 0..255
    const int qy = rest >> 4;             // q tile 0..15
    const int m0 = qy * 128;
    const int n0 = (rest & 15) * 128;     // k tile
    const __bf16* A  = Q  + (size_t)b * Ss * Dd;
    const __bf16* Bp = Km + (size_t)b * Ss * Dd;
    __bf16* C = P + (size_t)b * Ss * Ss;

    const int tid = threadIdx.x;
    const int wave = tid >> 6, lane = tid & 63, quad = lane >> 4, l16 = lane & 15;
    const int wm = (wave >> 1) * 64, wn = (wave & 1) * 64;
    const int swk = (quad ^ ((l16 >> 1) & 3)) * 8;
    const float scale = 0.044194173824159216f; // 1/sqrt(512)
    const float SHIFT = 8.0f;

    f32x4 acc[4][4];
    f32x4 zero = {0.f, 0.f, 0.f, 0.f};
    for (int i = 0; i < 4; i++) for (int j = 0; j < 4; j++) acc[i][j] = zero;

    stage32(As0, A  + (size_t)m0 * Dd, Dd, wave, lane);
    stage32(Bs0, Bp + (size_t)n0 * Dd, Dd, wave, lane);
    #pragma unroll 2
    for (int t = 0; t < 16; ++t) {
        ushort* Ac = (t & 1) ? As1 : As0;
        ushort* Bc = (t & 1) ? Bs1 : Bs0;
        if (t < 15) {
            ushort* An = (t & 1) ? As0 : As1;
            ushort* Bn = (t & 1) ? Bs0 : Bs1;
            const int kn = (t + 1) * 32;
            stage32(An, A  + (size_t)m0 * Dd + kn, Dd, wave, lane);
            stage32(Bn, Bp + (size_t)n0 * Dd + kn, Dd, wave, lane);
            asm volatile("s_waitcnt vmcnt(4)" ::: "memory");
        } else {
            asm volatile("s_waitcnt vmcnt(0)" ::: "memory");
        }
        __builtin_amdgcn_s_barrier();
        bf16x8 af[4], bfr[4];
        for (int i = 0; i < 4; i++) af[i]  = *(bf16x8*)&Ac[(wm + i * 16 + l16) * 32 + swk];
        for (int j = 0; j < 4; j++) bfr[j] = *(bf16x8*)&Bc[(wn + j * 16 + l16) * 32 + swk];
        for (int i = 0; i < 4; i++)
            for (int j = 0; j < 4; j++)
                acc[i][j] = __builtin_amdgcn_mfma_f32_16x16x32_bf16(af[i], bfr[j], acc[i][j], 0, 0, 0);
        __builtin_amdgcn_sched_barrier(0);
        __builtin_amdgcn_s_barrier();
    }

    // ---- exp -> per-wave LDS patch (swizzled, reuses smem) + column sums ----
    float* Ls = stats;                    // 256 f32
    const int half = wave >> 1;
    ushort* patch = smem + wave * 4096;   // 64x64 bf16
    float lj[4];
    for (int j = 0; j < 4; j++) {
        float l = 0.f;
        const int colsw = (j * 16 + l16) ^ (quad * 16);
        for (int i = 0; i < 4; i++)
            for (int rr = 0; rr < 4; rr++) {
                const float e = __expf(fmaf(acc[i][j][rr], scale, -SHIFT));
                const __bf16 pb = (__bf16)e;   // RNE
                patch[(i * 16 + quad * 4 + rr) * 64 + colsw] = *(const ushort*)&pb;
                l += e;
            }
        l += __shfl_xor(l, 16);
        l += __shfl_xor(l, 32);
        lj[j] = l;
    }
    if (quad == 0)
        for (int j = 0; j < 4; j++) Ls[half * 128 + wn + j * 16 + l16] = lj[j];
    __syncthreads();
    if (tid < 128) {
        const size_t o = ((size_t)qy * Bb + b) * Ss + n0 + tid;
        Lp[o] = Ls[tid] + Ls[128 + tid];
    }
    // ---- coalesced P store: 8 bf16x8 per thread ----
    #pragma unroll
    for (int it = 0; it < 8; it++) {
        const int lr = it * 8 + (lane >> 3);
        const int lc = ((lane & 7) * 8) ^ (((lr >> 2) & 3) * 16);
        const bf16x8 v = *(const bf16x8*)&patch[lr * 64 + lc];
        *(bf16x8*)&C[(size_t)(m0 + wm + lr) * Ss + n0 + wn + ((lane & 7) * 8)] = v;
    }
}

// ---------------------------------------------------------------------------
// Cinv[b][k] = 1 / sum_qy Lp[qy][b][k]
// ---------------------------------------------------------------------------
__global__ void stats_combine(const float* __restrict__ Lp, float* __restrict__ Cinv) {
    const int idx = blockIdx.x * 256 + threadIdx.x;  // over B*S columns
    float l = 0.f;
    for (int qy = 0; qy < QSPLIT; qy++) l += Lp[(size_t)qy * Bb * Ss + idx];
    Cinv[idx] = 1.0f / l;
}

// ---------------------------------------------------------------------------
// xscale: XC[b,e,k] = xT[b,e,k] * Cinv[b,k].  One block per (b,e) row.
// ---------------------------------------------------------------------------
__global__ void xscale_kernel(const __bf16* __restrict__ xT,
                              const float* __restrict__ Cinv,
                              __bf16* __restrict__ XC) {
    const int r = blockIdx.x;              // b*E + e  (4096 rows)
    const int b = r >> 9;                  // E = 512
    const size_t base = (size_t)r * Ss;
    const float* cp = Cinv + (size_t)b * Ss;
    const int k0 = threadIdx.x * 8;
    const bf16x8 v = *(const bf16x8*)&xT[base + k0];
    const float4 c0 = *(const float4*)&cp[k0];
    const float4 c1 = *(const float4*)&cp[k0 + 4];
    bf16x8 o;
    o[0] = (__bf16)((float)v[0] * c0.x);
    o[1] = (__bf16)((float)v[1] * c0.y);
    o[2] = (__bf16)((float)v[2] * c0.z);
    o[3] = (__bf16)((float)v[3] * c0.w);
    o[4] = (__bf16)((float)v[4] * c1.x);
    o[5] = (__bf16)((float)v[5] * c1.y);
    o[6] = (__bf16)((float)v[6] * c1.z);
    o[7] = (__bf16)((float)v[7] * c1.w);
    *(bf16x8*)&XC[base + k0] = o;
}

// ---------------------------------------------------------------------------
// PV GEMM (NT) — pure GEMM: Out = P @ XC + XB.  64x128 tile, 4 waves
// (wave tile 32x64), BK=64, 32 K-steps, 2-phase dbuf pipeline (R7-proven;
// BK=32 regressed here per R8 — 8 MFMA/step is below the sync-overhead floor).
// ---------------------------------------------------------------------------
__global__ __launch_bounds__(256, 4) void pv_kernel(
    const __bf16* __restrict__ P,    // [B,S,S] bf16 shifted exp scores
    const __bf16* __restrict__ XC,   // [B,E,S] bf16 x^T pre-scaled by 1/l[k]
    const __bf16* __restrict__ XB,   // [B,S,E] bf16 (residual)
    float* __restrict__ Out)         // [B,S,E] f32
{
    __shared__ __align__(16) ushort smem[2 * (64 * 64 + 128 * 64)];  // 48 KB dbuf
    ushort* As0 = smem;                 // 64x64
    ushort* Bs0 = smem + 4096;          // 128x64
    ushort* As1 = smem + 12288;
    ushort* Bs1 = smem + 16384;
    const int id = blockIdx.x;            // 0..1023
    const int b = id & 7;
    const int rest = id >> 3;             // 0..127
    const int m0 = (rest >> 2) * 64;      // q tile (64 rows)
    const int n0 = (rest & 3) * 128;      // e tile
    const __bf16* A  = P  + (size_t)b * Ss * Ss;
    const __bf16* Bp = XC + (size_t)b * Ee * Ss;

    const int tid = threadIdx.x;
    const int wave = tid >> 6, lane = tid & 63, quad = lane >> 4, l16 = lane & 15;
    const int wm = (wave >> 1) * 32, wn = (wave & 1) * 64;
    const int sw0 = ((quad)     ^ (l16 & 7)) * 8;
    const int sw1 = ((quad + 4) ^ (l16 & 7)) * 8;

    f32x4 acc[2][4];
    f32x4 zero = {0.f, 0.f, 0.f, 0.f};
    for (int i = 0; i < 2; i++) for (int j = 0; j < 4; j++) acc[i][j] = zero;

    stage64h(As0, A  + (size_t)m0 * Ss, Ss, wave, lane);
    stage64 (Bs0, Bp + (size_t)n0 * Ss, Ss, wave, lane);
    #pragma unroll 2
    for (int t = 0; t < 32; ++t) {
        ushort* Ac = (t & 1) ? As1 : As0;
        ushort* Bc = (t & 1) ? Bs1 : Bs0;
        if (t < 31) {
            ushort* An = (t & 1) ? As0 : As1;
            ushort* Bn = (t & 1) ? Bs0 : Bs1;
            const int kn = (t + 1) * 64;
            stage64h(An, A  + (size_t)m0 * Ss + kn, Ss, wave, lane);
            stage64 (Bn, Bp + (size_t)n0 * Ss + kn, Ss, wave, lane);
            asm volatile("s_waitcnt vmcnt(6)" ::: "memory");
        } else {
            asm volatile("s_waitcnt vmcnt(0)" ::: "memory");
        }
        __builtin_amdgcn_s_barrier();
        #pragma unroll
        for (int h = 0; h < 2; h++) {
            const int sw = h ? sw1 : sw0;
            bf16x8 af[2], bfr[4];
            for (int i = 0; i < 2; i++) af[i]  = *(bf16x8*)&Ac[(wm + i * 16 + l16) * 64 + sw];
            for (int j = 0; j < 4; j++) bfr[j] = *(bf16x8*)&Bc[(wn + j * 16 + l16) * 64 + sw];
            for (int i = 0; i < 2; i++)
                for (int j = 0; j < 4; j++)
                    acc[i][j] = __builtin_amdgcn_mfma_f32_16x16x32_bf16(af[i], bfr[j], acc[i][j], 0, 0, 0);
        }
        __builtin_amdgcn_sched_barrier(0);
        __builtin_amdgcn_s_barrier();
    }

    for (int i = 0; i < 2; i++) {
        for (int j = 0; j < 4; j++) {
            const int col = n0 + wn + j * 16 + l16;
            for (int rr = 0; rr < 4; rr++) {
                const int row = m0 + wm + i * 16 + quad * 4 + rr;
                const size_t idx = ((size_t)b * Ss + row) * Ee + col;
                Out[idx] = (float)XB[idx] + acc[i][j][rr];
            }
        }
    }
}

// ---------------------------------------------------------------------------
extern "C" void kernel_launch(void* const* d_in, const int* in_sizes, int n_in,
                              void* d_out, int out_size, void* d_ws, size_t ws_size,
                              hipStream_t stream) {
    const float* x  = (const float*)d_in[0];
    const float* Wq = (const float*)d_in[1];
    const float* bq = (const float*)d_in[2];
    const float* Wk = (const float*)d_in[3];
    const float* bk = (const float*)d_in[4];
    float* out = (float*)d_out;

    char* ws = (char*)d_ws;
    size_t off = 0;
    auto alloc = [&](size_t bytes) -> void* {
        void* p = ws + off;
        off += (bytes + 255) & ~(size_t)255;
        return p;
    };
    __bf16* P    = (__bf16*)alloc((size_t)Bb * Ss * Ss * 2);      // 64 MiB
    __bf16* xb   = (__bf16*)alloc((size_t)Bb * Ss * Ee * 2);
    __bf16* qb   = (__bf16*)alloc((size_t)Bb * Ss * Dd * 2);
    __bf16* kb   = (__bf16*)alloc((size_t)Bb * Ss * Dd * 2);
    __bf16* xT   = (__bf16*)alloc((size_t)Bb * Ee * Ss * 2);
    __bf16* WqT  = (__bf16*)alloc((size_t)512 * 512 * 2);
    __bf16* WkT  = (__bf16*)alloc((size_t)512 * 512 * 2);
    float*  Lp   = (float*)alloc((size_t)QSPLIT * Bb * Ss * 4);   // 1 MiB
    float*  Cinv = (float*)alloc((size_t)Bb * Ss * 4);            // 64 KiB
    if (off > ws_size) return;
    __bf16* XC = qb;   // reuse: qb is dead after scores_kernel (stream-ordered)

    prep_x<<<dim3(8, 32, 8), 256, 0, stream>>>(x, xb, xT);
    transpose_w<<<dim3(16, 16, 2), dim3(32, 8), 0, stream>>>(Wq, Wk, WqT, WkT);

    // q = relu(x Wq + bq), k = relu(x Wk + bk)
    proj_kernel<<<dim3(4, 128, 2), 256, 0, stream>>>(xb, WqT, WkT, bq, bk, qb, kb);

    // P = exp(q k^T / sqrt(E) - 8) bf16 + column-sum partials
    scores_kernel<<<dim3(2048), 256, 0, stream>>>(qb, kb, P, Lp);
    stats_combine<<<dim3(Bb * Ss / 256), 256, 0, stream>>>(Lp, Cinv);

    // XC = x^T / l[k]   (folds the softmax normalizer into the PV B-operand)
    xscale_kernel<<<dim3(Bb * Ee), 256, 0, stream>>>(xT, Cinv, XC);

    // out = x + P @ XC   (pure GEMM, residual fused)
    pv_kernel<<<dim3(1024), 256, 0, stream>>>(P, XC, xb, out);
}

// Round 10
// 208.367 us; speedup vs baseline: 1.1062x; 1.0105x over previous
//
#include <hip/hip_runtime.h>
#include <hip/hip_bf16.h>
#include <math.h>

// Problem constants (B, S, E, D) for SA_Layer_45603962749650
#define Bb 8
#define Ss 2048
#define Ee 512
#define Dd 512
#define QSPLIT 16   // one partial per 128-row scores tile

typedef __bf16 bf16x8 __attribute__((ext_vector_type(8)));
typedef __bf16 bf16x4 __attribute__((ext_vector_type(4)));
typedef float f32x4 __attribute__((ext_vector_type(4)));

// ---------------------------------------------------------------------------
// Column softmax via fixed global shift:
//   P[q,k]   = exp(s[q,k]*scale - SHIFT)          (s >= 0 since q,k = relu(..))
//   l[k]     = sum_q P[q,k]
//   out[q,e] = x[q,e] + sum_k P[q,k] * (x[k,e]/l[k])
// Normalizer indexes the CONTRACTION axis k -> folds into x (XC): PV is pure
// NT GEMM.
//
// R9 post-mortem: 210.6us best; per-kernel sum ~144us -> ~65us lives in the 6
// kernel boundaries (~10us each: graph-node drain + tail + launch). R10 tests
// that theory: 7 -> 5 launches by (a) folding transpose_w into prep_x
// (block-uniform branch on flattened grid) and (b) folding stats_combine into
// xscale (per-block Cinv recompute in LDS, same summation order ->
// bit-identical). GEMM kernels are byte-identical to R9.
// ---------------------------------------------------------------------------

// ---------------------------------------------------------------------------
// BK=64 async staging: 128x64 tile (16 KB), 4-wave blocks, 4 loads/thread.
// Slot s (0..1023): row = s>>3, phys chunk = s&7, data chunk c = (s&7)^(row&7).
// LDS dest = wave-uniform base + lane*16 (m104-safe).
// ---------------------------------------------------------------------------
__device__ __forceinline__ void stage64(ushort* lds, const __bf16* gbase,
                                        int ldg, int wave, int lane) {
#pragma unroll
    for (int t = 0; t < 4; ++t) {
        const int slot = wave * 256 + t * 64 + lane;
        const int row  = slot >> 3;
        const int c    = (slot & 7) ^ (row & 7);
        __builtin_amdgcn_global_load_lds(
            (const __attribute__((address_space(1))) void*)(gbase + (size_t)row * ldg + c * 8),
            (__attribute__((address_space(3))) void*)(lds + (size_t)slot * 8),
            16, 0, 0);
    }
}

// Same layout, 64-row x 64-col tile (8 KB): 512 slots, 2 loads/thread.
__device__ __forceinline__ void stage64h(ushort* lds, const __bf16* gbase,
                                         int ldg, int wave, int lane) {
#pragma unroll
    for (int t = 0; t < 2; ++t) {
        const int slot = wave * 128 + t * 64 + lane;
        const int row  = slot >> 3;
        const int c    = (slot & 7) ^ (row & 7);
        __builtin_amdgcn_global_load_lds(
            (const __attribute__((address_space(1))) void*)(gbase + (size_t)row * ldg + c * 8),
            (__attribute__((address_space(3))) void*)(lds + (size_t)slot * 8),
            16, 0, 0);
    }
}

// BK=32 async staging: 128x32 tile (8 KB), 512 slots, 2 loads/thread.
// Swizzle: data chunk c at phys p = c ^ ((row>>1)&3); read phys =
// quad ^ ((l16>>1)&3) -> conflict-free (verified R7: SQ_LDS_BANK_CONFLICT = 0).
__device__ __forceinline__ void stage32(ushort* lds, const __bf16* gbase,
                                        int ldg, int wave, int lane) {
#pragma unroll
    for (int t = 0; t < 2; ++t) {
        const int slot = wave * 128 + t * 64 + lane;
        const int row  = slot >> 2;
        const int c    = (slot & 3) ^ ((row >> 1) & 3);
        __builtin_amdgcn_global_load_lds(
            (const __attribute__((address_space(1))) void*)(gbase + (size_t)row * ldg + c * 8),
            (__attribute__((address_space(3))) void*)(lds + (size_t)slot * 8),
            16, 0, 0);
    }
}

// ---------------------------------------------------------------------------
// prep_fused: blocks 0..2047 = prep_x path (xb = bf16(x), xT = bf16(x^T));
// blocks 2048..2559 = transpose_w path (WqT/WkT = bf16(W^T)).
// Branch is block-uniform. LDS tile reused by both paths (65-stride, odd ->
// conflict-free for both 64- and 32-wide transposes).
// ---------------------------------------------------------------------------
__global__ __launch_bounds__(256) void prep_fused(
    const float* __restrict__ x,
    const float* __restrict__ Wq, const float* __restrict__ Wk,
    __bf16* __restrict__ xb, __bf16* __restrict__ xT,
    __bf16* __restrict__ WqT, __bf16* __restrict__ WkT)
{
    __shared__ float tile[64][65];
    const int bid = blockIdx.x;
    const int tid = threadIdx.x;
    if (bid < 2048) {
        // ---- prep_x: 64x64 f32 tile, float4 loads, bf16 vector stores ----
        const int e0 = (bid & 7) * 64;
        const int s0 = ((bid >> 3) & 31) * 64;
        const int b  = bid >> 8;
        const float* ip = x + (size_t)b * Ss * Ee;
        __bf16* xbp = xb + (size_t)b * Ss * Ee;
        __bf16* xTp = xT + (size_t)b * Ee * Ss;
        const int rrow = tid >> 4;        // 0..15
        const int c4   = (tid & 15) * 4;  // f32 column within tile
        #pragma unroll
        for (int it = 0; it < 4; ++it) {
            const int r = it * 16 + rrow;
            const float4 v = *(const float4*)&ip[(size_t)(s0 + r) * Ee + e0 + c4];
            bf16x4 h;
            h[0] = (__bf16)v.x; h[1] = (__bf16)v.y; h[2] = (__bf16)v.z; h[3] = (__bf16)v.w;
            *(bf16x4*)&xbp[(size_t)(s0 + r) * Ee + e0 + c4] = h;
            tile[r][c4 + 0] = v.x; tile[r][c4 + 1] = v.y;
            tile[r][c4 + 2] = v.z; tile[r][c4 + 3] = v.w;
        }
        __syncthreads();
        const int sc  = (tid & 7) * 8;    // s-chunk of 8
        const int erb = tid >> 3;         // 0..31
        #pragma unroll
        for (int it = 0; it < 2; ++it) {
            const int er = it * 32 + erb;
            bf16x8 o;
            #pragma unroll
            for (int t = 0; t < 8; ++t) o[t] = (__bf16)tile[sc + t][er];
            *(bf16x8*)&xTp[(size_t)(e0 + er) * Ss + s0 + sc] = o;
        }
    } else {
        // ---- transpose_w: 32x32 f32 tile -> bf16 ----
        const int t  = bid - 2048;        // 0..511
        const float* in = (t >> 8) ? Wk : Wq;
        __bf16* outp    = (t >> 8) ? WkT : WqT;
        const int x0 = (t & 15) * 32;
        const int y0 = ((t >> 4) & 15) * 32;
        const int tx = tid & 31, ty = tid >> 5;   // 32 x 8
        for (int i = ty; i < 32; i += 8)
            tile[i][tx] = in[(size_t)(y0 + i) * 512 + (x0 + tx)];
        __syncthreads();
        for (int i = ty; i < 32; i += 8)
            outp[(size_t)(x0 + i) * 512 + (y0 + tx)] = (__bf16)tile[tx][i];
    }
}

// ---------------------------------------------------------------------------
// Projection GEMM (NT): Out = relu(X @ W + b).  128x128 tile, BK=32 dbuf
// (32 KB -> 4 blocks/CU), 16 K-steps, 2-phase counted-vmcnt pipeline,
// swizzled epilogue store.  (Wave tile 64x64 = 16 MFMA/step: BK=32-safe.)
// ---------------------------------------------------------------------------
__global__ __launch_bounds__(256, 4) void proj_kernel(
    const __bf16* __restrict__ X,
    const __bf16* __restrict__ WqT, const __bf16* __restrict__ WkT,
    const float* __restrict__ bq, const float* __restrict__ bk,
    __bf16* __restrict__ qb, __bf16* __restrict__ kb)
{
    __shared__ __align__(16) ushort smem[4 * 128 * 32];   // As0|Bs0|As1|Bs1, 32 KB
    ushort* As0 = smem;
    ushort* Bs0 = smem + 4096;
    ushort* As1 = smem + 8192;
    ushort* Bs1 = smem + 12288;
    const __bf16* WT  = blockIdx.z ? WkT : WqT;
    const float* bias = blockIdx.z ? bk : bq;
    __bf16* Out       = blockIdx.z ? kb : qb;

    const int tid = threadIdx.x;
    const int wave = tid >> 6, lane = tid & 63, quad = lane >> 4, l16 = lane & 15;
    const int wm = (wave >> 1) * 64, wn = (wave & 1) * 64;
    const int m0 = blockIdx.y * 128, n0 = blockIdx.x * 128;
    const int K = 512;
    const int swk = (quad ^ ((l16 >> 1) & 3)) * 8;

    f32x4 acc[4][4];
    f32x4 zero = {0.f, 0.f, 0.f, 0.f};
    for (int i = 0; i < 4; i++) for (int j = 0; j < 4; j++) acc[i][j] = zero;

    stage32(As0, X  + (size_t)m0 * K, K, wave, lane);
    stage32(Bs0, WT + (size_t)n0 * K, K, wave, lane);
    #pragma unroll 2
    for (int t = 0; t < 16; ++t) {
        ushort* Ac = (t & 1) ? As1 : As0;
        ushort* Bc = (t & 1) ? Bs1 : Bs0;
        if (t < 15) {
            ushort* An = (t & 1) ? As0 : As1;
            ushort* Bn = (t & 1) ? Bs0 : Bs1;
            const int kn = (t + 1) * 32;
            stage32(An, X  + (size_t)m0 * K + kn, K, wave, lane);
            stage32(Bn, WT + (size_t)n0 * K + kn, K, wave, lane);
            asm volatile("s_waitcnt vmcnt(4)" ::: "memory");
        } else {
            asm volatile("s_waitcnt vmcnt(0)" ::: "memory");
        }
        __builtin_amdgcn_s_barrier();
        bf16x8 af[4], bfr[4];
        for (int i = 0; i < 4; i++) af[i]  = *(bf16x8*)&Ac[(wm + i * 16 + l16) * 32 + swk];
        for (int j = 0; j < 4; j++) bfr[j] = *(bf16x8*)&Bc[(wn + j * 16 + l16) * 32 + swk];
        for (int i = 0; i < 4; i++)
            for (int j = 0; j < 4; j++)
                acc[i][j] = __builtin_amdgcn_mfma_f32_16x16x32_bf16(af[i], bfr[j], acc[i][j], 0, 0, 0);
        __builtin_amdgcn_sched_barrier(0);
        __builtin_amdgcn_s_barrier();
    }

    // epilogue: bias+relu -> per-wave LDS patch (swizzled) -> coalesced stores
    ushort* patch = smem + wave * 4096;   // 64x64 bf16
    for (int j = 0; j < 4; j++) {
        const float bv = bias[n0 + wn + j * 16 + l16];
        const int colsw = (j * 16 + l16) ^ (quad * 16);
        for (int i = 0; i < 4; i++)
            for (int rr = 0; rr < 4; rr++) {
                float v = acc[i][j][rr] + bv;
                v = v > 0.f ? v : 0.f;
                patch[(i * 16 + quad * 4 + rr) * 64 + colsw] = ((ushort2*)&v)[0].y;
            }
    }
    __syncthreads();
    #pragma unroll
    for (int it = 0; it < 8; it++) {
        const int lr = it * 8 + (lane >> 3);
        const int lc = ((lane & 7) * 8) ^ (((lr >> 2) & 3) * 16);
        const bf16x8 v = *(const bf16x8*)&patch[lr * 64 + lc];
        *(bf16x8*)&Out[(size_t)(m0 + wm + lr) * 512 + n0 + wn + (((lane & 7) * 8))] = v;
    }
}

// ---------------------------------------------------------------------------
// Scores GEMM (NT), BK=32 dbuf (32 KB -> 4 blocks/CU), 16 K-steps, 2-phase
// counted-vmcnt pipeline, conflict-free swizzle (R7-verified).
// P = exp(s*scale - SHIFT) bf16 via swizzled LDS patch + column sums Lp.
// 1-D grid, XCD=batch swizzle.
// ---------------------------------------------------------------------------
__global__ __launch_bounds__(256, 4) void scores_kernel(
    const __bf16* __restrict__ Q,   // [B*S, D] bf16
    const __bf16* __restrict__ Km,  // [B*S, D] bf16
    __bf16* __restrict__ P,         // [B, S, S] bf16
    float* __restrict__ Lp)         // [QSPLIT, B, S] partial column sums
{
    __shared__ __align__(16) ushort smem[4 * 128 * 32];   // As0|Bs0|As1|Bs1, 32 KB
    __shared__ float stats[256];                          // Ls
    ushort* As0 = smem;
    ushort* Bs0 = smem + 4096;
    ushort* As1 = smem + 8192;
    ushort* Bs1 = smem + 12288;
    const int id = blockIdx.x;            // 0..2047
    const int b = id & 7;
    const int rest = id >> 3;             // 0..255
    const int qy = rest >> 4;             // q tile 0..15
    const int m0 = qy * 128;
    const int n0 = (rest & 15) * 128;     // k tile
    const __bf16* A  = Q  + (size_t)b * Ss * Dd;
    const __bf16* Bp = Km + (size_t)b * Ss * Dd;
    __bf16* C = P + (size_t)b * Ss * Ss;

    const int tid = threadIdx.x;
    const int wave = tid >> 6, lane = tid & 63, quad = lane >> 4, l16 = lane & 15;
    const int wm = (wave >> 1) * 64, wn = (wave & 1) * 64;
    const int swk = (quad ^ ((l16 >> 1) & 3)) * 8;
    const float scale = 0.044194173824159216f; // 1/sqrt(512)
    const float SHIFT = 8.0f;

    f32x4 acc[4][4];
    f32x4 zero = {0.f, 0.f, 0.f, 0.f};
    for (int i = 0; i < 4; i++) for (int j = 0; j < 4; j++) acc[i][j] = zero;

    stage32(As0, A  + (size_t)m0 * Dd, Dd, wave, lane);
    stage32(Bs0, Bp + (size_t)n0 * Dd, Dd, wave, lane);
    #pragma unroll 2
    for (int t = 0; t < 16; ++t) {
        ushort* Ac = (t & 1) ? As1 : As0;
        ushort* Bc = (t & 1) ? Bs1 : Bs0;
        if (t < 15) {
            ushort* An = (t & 1) ? As0 : As1;
            ushort* Bn = (t & 1) ? Bs0 : Bs1;
            const int kn = (t + 1) * 32;
            stage32(An, A  + (size_t)m0 * Dd + kn, Dd, wave, lane);
            stage32(Bn, Bp + (size_t)n0 * Dd + kn, Dd, wave, lane);
            asm volatile("s_waitcnt vmcnt(4)" ::: "memory");
        } else {
            asm volatile("s_waitcnt vmcnt(0)" ::: "memory");
        }
        __builtin_amdgcn_s_barrier();
        bf16x8 af[4], bfr[4];
        for (int i = 0; i < 4; i++) af[i]  = *(bf16x8*)&Ac[(wm + i * 16 + l16) * 32 + swk];
        for (int j = 0; j < 4; j++) bfr[j] = *(bf16x8*)&Bc[(wn + j * 16 + l16) * 32 + swk];
        for (int i = 0; i < 4; i++)
            for (int j = 0; j < 4; j++)
                acc[i][j] = __builtin_amdgcn_mfma_f32_16x16x32_bf16(af[i], bfr[j], acc[i][j], 0, 0, 0);
        __builtin_amdgcn_sched_barrier(0);
        __builtin_amdgcn_s_barrier();
    }

    // ---- exp -> per-wave LDS patch (swizzled, reuses smem) + column sums ----
    float* Ls = stats;                    // 256 f32
    const int half = wave >> 1;
    ushort* patch = smem + wave * 4096;   // 64x64 bf16
    float lj[4];
    for (int j = 0; j < 4; j++) {
        float l = 0.f;
        const int colsw = (j * 16 + l16) ^ (quad * 16);
        for (int i = 0; i < 4; i++)
            for (int rr = 0; rr < 4; rr++) {
                const float e = __expf(fmaf(acc[i][j][rr], scale, -SHIFT));
                const __bf16 pb = (__bf16)e;   // RNE
                patch[(i * 16 + quad * 4 + rr) * 64 + colsw] = *(const ushort*)&pb;
                l += e;
            }
        l += __shfl_xor(l, 16);
        l += __shfl_xor(l, 32);
        lj[j] = l;
    }
    if (quad == 0)
        for (int j = 0; j < 4; j++) Ls[half * 128 + wn + j * 16 + l16] = lj[j];
    __syncthreads();
    if (tid < 128) {
        const size_t o = ((size_t)qy * Bb + b) * Ss + n0 + tid;
        Lp[o] = Ls[tid] + Ls[128 + tid];
    }
    // ---- coalesced P store: 8 bf16x8 per thread ----
    #pragma unroll
    for (int it = 0; it < 8; it++) {
        const int lr = it * 8 + (lane >> 3);
        const int lc = ((lane & 7) * 8) ^ (((lr >> 2) & 3) * 16);
        const bf16x8 v = *(const bf16x8*)&patch[lr * 64 + lc];
        *(bf16x8*)&C[(size_t)(m0 + wm + lr) * Ss + n0 + wn + ((lane & 7) * 8)] = v;
    }
}

// ---------------------------------------------------------------------------
// csx_kernel: fused stats_combine + xscale.
// Grid 512 = 8 b x 64 groups of 8 e-rows. Each block recomputes the full
// Cinv[b][:] into LDS (same qy summation order as the old stats_combine ->
// bit-identical), then XC[b,e,k] = xT[b,e,k] * Cinv[b,k] for its 8 rows.
// Redundant Cinv work: 512 blocks x 128 KB Lp reads = 64 MB L2 (~2 us).
// ---------------------------------------------------------------------------
__global__ __launch_bounds__(256) void csx_kernel(const float* __restrict__ Lp,
                                                  const __bf16* __restrict__ xT,
                                                  __bf16* __restrict__ XC) {
    __shared__ float cinv[2048];
    const int b = blockIdx.x >> 6;        // 0..7
    const int g = blockIdx.x & 63;        // 0..63
    const int tid = threadIdx.x;
    const int k0 = tid * 8;
    float s[8];
    #pragma unroll
    for (int u = 0; u < 8; ++u) s[u] = 0.f;
    for (int qy = 0; qy < QSPLIT; ++qy) {
        const float* lp = Lp + ((size_t)qy * Bb + b) * Ss + k0;
        const float4 a0 = *(const float4*)lp;
        const float4 a1 = *(const float4*)(lp + 4);
        s[0] += a0.x; s[1] += a0.y; s[2] += a0.z; s[3] += a0.w;
        s[4] += a1.x; s[5] += a1.y; s[6] += a1.z; s[7] += a1.w;
    }
    #pragma unroll
    for (int u = 0; u < 8; ++u) cinv[k0 + u] = 1.0f / s[u];
    __syncthreads();
    const float4 c0 = *(const float4*)&cinv[k0];
    const float4 c1 = *(const float4*)&cinv[k0 + 4];
    #pragma unroll
    for (int r = 0; r < 8; ++r) {
        const int e = g * 8 + r;
        const size_t base = ((size_t)b * Ee + e) * Ss;
        const bf16x8 v = *(const bf16x8*)&xT[base + k0];
        bf16x8 o;
        o[0] = (__bf16)((float)v[0] * c0.x);
        o[1] = (__bf16)((float)v[1] * c0.y);
        o[2] = (__bf16)((float)v[2] * c0.z);
        o[3] = (__bf16)((float)v[3] * c0.w);
        o[4] = (__bf16)((float)v[4] * c1.x);
        o[5] = (__bf16)((float)v[5] * c1.y);
        o[6] = (__bf16)((float)v[6] * c1.z);
        o[7] = (__bf16)((float)v[7] * c1.w);
        *(bf16x8*)&XC[base + k0] = o;
    }
}

// ---------------------------------------------------------------------------
// PV GEMM (NT) — pure GEMM: Out = P @ XC + XB.  64x128 tile, 4 waves
// (wave tile 32x64), BK=64, 32 K-steps, 2-phase dbuf pipeline (R7-proven;
// BK=32 regressed here per R8 — 8 MFMA/step is below the sync-overhead floor).
// ---------------------------------------------------------------------------
__global__ __launch_bounds__(256, 4) void pv_kernel(
    const __bf16* __restrict__ P,    // [B,S,S] bf16 shifted exp scores
    const __bf16* __restrict__ XC,   // [B,E,S] bf16 x^T pre-scaled by 1/l[k]
    const __bf16* __restrict__ XB,   // [B,S,E] bf16 (residual)
    float* __restrict__ Out)         // [B,S,E] f32
{
    __shared__ __align__(16) ushort smem[2 * (64 * 64 + 128 * 64)];  // 48 KB dbuf
    ushort* As0 = smem;                 // 64x64
    ushort* Bs0 = smem + 4096;          // 128x64
    ushort* As1 = smem + 12288;
    ushort* Bs1 = smem + 16384;
    const int id = blockIdx.x;            // 0..1023
    const int b = id & 7;
    const int rest = id >> 3;             // 0..127
    const int m0 = (rest >> 2) * 64;      // q tile (64 rows)
    const int n0 = (rest & 3) * 128;      // e tile
    const __bf16* A  = P  + (size_t)b * Ss * Ss;
    const __bf16* Bp = XC + (size_t)b * Ee * Ss;

    const int tid = threadIdx.x;
    const int wave = tid >> 6, lane = tid & 63, quad = lane >> 4, l16 = lane & 15;
    const int wm = (wave >> 1) * 32, wn = (wave & 1) * 64;
    const int sw0 = ((quad)     ^ (l16 & 7)) * 8;
    const int sw1 = ((quad + 4) ^ (l16 & 7)) * 8;

    f32x4 acc[2][4];
    f32x4 zero = {0.f, 0.f, 0.f, 0.f};
    for (int i = 0; i < 2; i++) for (int j = 0; j < 4; j++) acc[i][j] = zero;

    stage64h(As0, A  + (size_t)m0 * Ss, Ss, wave, lane);
    stage64 (Bs0, Bp + (size_t)n0 * Ss, Ss, wave, lane);
    #pragma unroll 2
    for (int t = 0; t < 32; ++t) {
        ushort* Ac = (t & 1) ? As1 : As0;
        ushort* Bc = (t & 1) ? Bs1 : Bs0;
        if (t < 31) {
            ushort* An = (t & 1) ? As0 : As1;
            ushort* Bn = (t & 1) ? Bs0 : Bs1;
            const int kn = (t + 1) * 64;
            stage64h(An, A  + (size_t)m0 * Ss + kn, Ss, wave, lane);
            stage64 (Bn, Bp + (size_t)n0 * Ss + kn, Ss, wave, lane);
            asm volatile("s_waitcnt vmcnt(6)" ::: "memory");
        } else {
            asm volatile("s_waitcnt vmcnt(0)" ::: "memory");
        }
        __builtin_amdgcn_s_barrier();
        #pragma unroll
        for (int h = 0; h < 2; h++) {
            const int sw = h ? sw1 : sw0;
            bf16x8 af[2], bfr[4];
            for (int i = 0; i < 2; i++) af[i]  = *(bf16x8*)&Ac[(wm + i * 16 + l16) * 64 + sw];
            for (int j = 0; j < 4; j++) bfr[j] = *(bf16x8*)&Bc[(wn + j * 16 + l16) * 64 + sw];
            for (int i = 0; i < 2; i++)
                for (int j = 0; j < 4; j++)
                    acc[i][j] = __builtin_amdgcn_mfma_f32_16x16x32_bf16(af[i], bfr[j], acc[i][j], 0, 0, 0);
        }
        __builtin_amdgcn_sched_barrier(0);
        __builtin_amdgcn_s_barrier();
    }

    for (int i = 0; i < 2; i++) {
        for (int j = 0; j < 4; j++) {
            const int col = n0 + wn + j * 16 + l16;
            for (int rr = 0; rr < 4; rr++) {
                const int row = m0 + wm + i * 16 + quad * 4 + rr;
                const size_t idx = ((size_t)b * Ss + row) * Ee + col;
                Out[idx] = (float)XB[idx] + acc[i][j][rr];
            }
        }
    }
}

// ---------------------------------------------------------------------------
extern "C" void kernel_launch(void* const* d_in, const int* in_sizes, int n_in,
                              void* d_out, int out_size, void* d_ws, size_t ws_size,
                              hipStream_t stream) {
    const float* x  = (const float*)d_in[0];
    const float* Wq = (const float*)d_in[1];
    const float* bq = (const float*)d_in[2];
    const float* Wk = (const float*)d_in[3];
    const float* bk = (const float*)d_in[4];
    float* out = (float*)d_out;

    char* ws = (char*)d_ws;
    size_t off = 0;
    auto alloc = [&](size_t bytes) -> void* {
        void* p = ws + off;
        off += (bytes + 255) & ~(size_t)255;
        return p;
    };
    __bf16* P    = (__bf16*)alloc((size_t)Bb * Ss * Ss * 2);      // 64 MiB
    __bf16* xb   = (__bf16*)alloc((size_t)Bb * Ss * Ee * 2);
    __bf16* qb   = (__bf16*)alloc((size_t)Bb * Ss * Dd * 2);
    __bf16* kb   = (__bf16*)alloc((size_t)Bb * Ss * Dd * 2);
    __bf16* xT   = (__bf16*)alloc((size_t)Bb * Ee * Ss * 2);
    __bf16* WqT  = (__bf16*)alloc((size_t)512 * 512 * 2);
    __bf16* WkT  = (__bf16*)alloc((size_t)512 * 512 * 2);
    float*  Lp   = (float*)alloc((size_t)QSPLIT * Bb * Ss * 4);   // 1 MiB
    if (off > ws_size) return;
    __bf16* XC = qb;   // reuse: qb is dead after scores_kernel (stream-ordered)

    // xb, xT, WqT, WkT in one launch
    prep_fused<<<dim3(2048 + 512), 256, 0, stream>>>(x, Wq, Wk, xb, xT, WqT, WkT);

    // q = relu(x Wq + bq), k = relu(x Wk + bk)
    proj_kernel<<<dim3(4, 128, 2), 256, 0, stream>>>(xb, WqT, WkT, bq, bk, qb, kb);

    // P = exp(q k^T / sqrt(E) - 8) bf16 + column-sum partials
    scores_kernel<<<dim3(2048), 256, 0, stream>>>(qb, kb, P, Lp);

    // XC = x^T / l[k]   (fused normalizer combine + scale)
    csx_kernel<<<dim3(512), 256, 0, stream>>>(Lp, xT, XC);

    // out = x + P @ XC   (pure GEMM, residual fused)
    pv_kernel<<<dim3(1024), 256, 0, stream>>>(P, XC, xb, out);
}

// Round 11
// 206.109 us; speedup vs baseline: 1.1183x; 1.0110x over previous
//
#include <hip/hip_runtime.h>
#include <hip/hip_bf16.h>
#include <math.h>

// Problem constants (B, S, E, D) for SA_Layer_45603962749650
#define Bb 8
#define Ss 2048
#define Ee 512
#define Dd 512
#define QSPLIT 16   // one partial per 128-row scores tile

typedef __bf16 bf16x8 __attribute__((ext_vector_type(8)));
typedef __bf16 bf16x4 __attribute__((ext_vector_type(4)));
typedef float f32x4 __attribute__((ext_vector_type(4)));

// ---------------------------------------------------------------------------
// Column softmax via fixed global shift:
//   P[q,k]   = exp(s[q,k]*scale - SHIFT)          (s >= 0 since q,k = relu(..))
//   l[k]     = sum_q P[q,k]
//   out[q,e] = x[q,e] + sum_k P[q,k] * (x[k,e]/l[k])
// Normalizer indexes the CONTRACTION axis k -> folds into x (XC): PV is pure
// NT GEMM.
//
// R10 post-mortem: launch-fusion gained only ~2us -> boundary cost ~1us each,
// not 10. Ledger audit: scores 1-phase BK=64 measured 46.8us (R2) vs 50.8-53.2
// for every 2-phase variant (R3-R10); pv 1-phase measured 45.6us (R2).
// 2-phase + sched_barrier(0) pinning never beat 1-phase here (m114 implicit
// wave-overlap already hides staging at 4 blocks/CU; m141: pinning hurts).
// proj's BK=32 2-phase DID measure faster (R9 vs R7, ~4us).
// R11 = best-measured variant per kernel: scores/pv reverted to R2 1-phase
// loops; proj/prep_fused/csx kept from R10. Bit-identical numerics.
// ---------------------------------------------------------------------------

// ---------------------------------------------------------------------------
// BK=64 async staging: 128x64 tile (16 KB), 4-wave blocks, 4 loads/thread.
// Slot s (0..1023): row = s>>3, phys chunk = s&7, data chunk c = (s&7)^(row&7).
// LDS dest = wave-uniform base + lane*16 (m104-safe).
// ---------------------------------------------------------------------------
__device__ __forceinline__ void stage64(ushort* lds, const __bf16* gbase,
                                        int ldg, int wave, int lane) {
#pragma unroll
    for (int t = 0; t < 4; ++t) {
        const int slot = wave * 256 + t * 64 + lane;
        const int row  = slot >> 3;
        const int c    = (slot & 7) ^ (row & 7);
        __builtin_amdgcn_global_load_lds(
            (const __attribute__((address_space(1))) void*)(gbase + (size_t)row * ldg + c * 8),
            (__attribute__((address_space(3))) void*)(lds + (size_t)slot * 8),
            16, 0, 0);
    }
}

// Same layout, 64-row x 64-col tile (8 KB): 512 slots, 2 loads/thread.
__device__ __forceinline__ void stage64h(ushort* lds, const __bf16* gbase,
                                         int ldg, int wave, int lane) {
#pragma unroll
    for (int t = 0; t < 2; ++t) {
        const int slot = wave * 128 + t * 64 + lane;
        const int row  = slot >> 3;
        const int c    = (slot & 7) ^ (row & 7);
        __builtin_amdgcn_global_load_lds(
            (const __attribute__((address_space(1))) void*)(gbase + (size_t)row * ldg + c * 8),
            (__attribute__((address_space(3))) void*)(lds + (size_t)slot * 8),
            16, 0, 0);
    }
}

// BK=32 async staging: 128x32 tile (8 KB), 512 slots, 2 loads/thread.
// Swizzle: data chunk c at phys p = c ^ ((row>>1)&3); read phys =
// quad ^ ((l16>>1)&3) -> conflict-free (verified R7: SQ_LDS_BANK_CONFLICT = 0).
__device__ __forceinline__ void stage32(ushort* lds, const __bf16* gbase,
                                        int ldg, int wave, int lane) {
#pragma unroll
    for (int t = 0; t < 2; ++t) {
        const int slot = wave * 128 + t * 64 + lane;
        const int row  = slot >> 2;
        const int c    = (slot & 3) ^ ((row >> 1) & 3);
        __builtin_amdgcn_global_load_lds(
            (const __attribute__((address_space(1))) void*)(gbase + (size_t)row * ldg + c * 8),
            (__attribute__((address_space(3))) void*)(lds + (size_t)slot * 8),
            16, 0, 0);
    }
}

// ---------------------------------------------------------------------------
// prep_fused: blocks 0..2047 = prep_x path (xb = bf16(x), xT = bf16(x^T));
// blocks 2048..2559 = transpose_w path (WqT/WkT = bf16(W^T)).
// ---------------------------------------------------------------------------
__global__ __launch_bounds__(256) void prep_fused(
    const float* __restrict__ x,
    const float* __restrict__ Wq, const float* __restrict__ Wk,
    __bf16* __restrict__ xb, __bf16* __restrict__ xT,
    __bf16* __restrict__ WqT, __bf16* __restrict__ WkT)
{
    __shared__ float tile[64][65];
    const int bid = blockIdx.x;
    const int tid = threadIdx.x;
    if (bid < 2048) {
        const int e0 = (bid & 7) * 64;
        const int s0 = ((bid >> 3) & 31) * 64;
        const int b  = bid >> 8;
        const float* ip = x + (size_t)b * Ss * Ee;
        __bf16* xbp = xb + (size_t)b * Ss * Ee;
        __bf16* xTp = xT + (size_t)b * Ee * Ss;
        const int rrow = tid >> 4;        // 0..15
        const int c4   = (tid & 15) * 4;  // f32 column within tile
        #pragma unroll
        for (int it = 0; it < 4; ++it) {
            const int r = it * 16 + rrow;
            const float4 v = *(const float4*)&ip[(size_t)(s0 + r) * Ee + e0 + c4];
            bf16x4 h;
            h[0] = (__bf16)v.x; h[1] = (__bf16)v.y; h[2] = (__bf16)v.z; h[3] = (__bf16)v.w;
            *(bf16x4*)&xbp[(size_t)(s0 + r) * Ee + e0 + c4] = h;
            tile[r][c4 + 0] = v.x; tile[r][c4 + 1] = v.y;
            tile[r][c4 + 2] = v.z; tile[r][c4 + 3] = v.w;
        }
        __syncthreads();
        const int sc  = (tid & 7) * 8;    // s-chunk of 8
        const int erb = tid >> 3;         // 0..31
        #pragma unroll
        for (int it = 0; it < 2; ++it) {
            const int er = it * 32 + erb;
            bf16x8 o;
            #pragma unroll
            for (int t = 0; t < 8; ++t) o[t] = (__bf16)tile[sc + t][er];
            *(bf16x8*)&xTp[(size_t)(e0 + er) * Ss + s0 + sc] = o;
        }
    } else {
        const int t  = bid - 2048;        // 0..511
        const float* in = (t >> 8) ? Wk : Wq;
        __bf16* outp    = (t >> 8) ? WkT : WqT;
        const int x0 = (t & 15) * 32;
        const int y0 = ((t >> 4) & 15) * 32;
        const int tx = tid & 31, ty = tid >> 5;   // 32 x 8
        for (int i = ty; i < 32; i += 8)
            tile[i][tx] = in[(size_t)(y0 + i) * 512 + (x0 + tx)];
        __syncthreads();
        for (int i = ty; i < 32; i += 8)
            outp[(size_t)(x0 + i) * 512 + (y0 + tx)] = (__bf16)tile[tx][i];
    }
}

// ---------------------------------------------------------------------------
// Projection GEMM (NT): Out = relu(X @ W + b).  128x128 tile, BK=32 dbuf
// (32 KB -> 4 blocks/CU), 16 K-steps, 2-phase counted-vmcnt pipeline,
// swizzled epilogue store.  (Measured faster than BK=64 variants: R9 vs R7.)
// ---------------------------------------------------------------------------
__global__ __launch_bounds__(256, 4) void proj_kernel(
    const __bf16* __restrict__ X,
    const __bf16* __restrict__ WqT, const __bf16* __restrict__ WkT,
    const float* __restrict__ bq, const float* __restrict__ bk,
    __bf16* __restrict__ qb, __bf16* __restrict__ kb)
{
    __shared__ __align__(16) ushort smem[4 * 128 * 32];   // As0|Bs0|As1|Bs1, 32 KB
    ushort* As0 = smem;
    ushort* Bs0 = smem + 4096;
    ushort* As1 = smem + 8192;
    ushort* Bs1 = smem + 12288;
    const __bf16* WT  = blockIdx.z ? WkT : WqT;
    const float* bias = blockIdx.z ? bk : bq;
    __bf16* Out       = blockIdx.z ? kb : qb;

    const int tid = threadIdx.x;
    const int wave = tid >> 6, lane = tid & 63, quad = lane >> 4, l16 = lane & 15;
    const int wm = (wave >> 1) * 64, wn = (wave & 1) * 64;
    const int m0 = blockIdx.y * 128, n0 = blockIdx.x * 128;
    const int K = 512;
    const int swk = (quad ^ ((l16 >> 1) & 3)) * 8;

    f32x4 acc[4][4];
    f32x4 zero = {0.f, 0.f, 0.f, 0.f};
    for (int i = 0; i < 4; i++) for (int j = 0; j < 4; j++) acc[i][j] = zero;

    stage32(As0, X  + (size_t)m0 * K, K, wave, lane);
    stage32(Bs0, WT + (size_t)n0 * K, K, wave, lane);
    #pragma unroll 2
    for (int t = 0; t < 16; ++t) {
        ushort* Ac = (t & 1) ? As1 : As0;
        ushort* Bc = (t & 1) ? Bs1 : Bs0;
        if (t < 15) {
            ushort* An = (t & 1) ? As0 : As1;
            ushort* Bn = (t & 1) ? Bs0 : Bs1;
            const int kn = (t + 1) * 32;
            stage32(An, X  + (size_t)m0 * K + kn, K, wave, lane);
            stage32(Bn, WT + (size_t)n0 * K + kn, K, wave, lane);
            asm volatile("s_waitcnt vmcnt(4)" ::: "memory");
        } else {
            asm volatile("s_waitcnt vmcnt(0)" ::: "memory");
        }
        __builtin_amdgcn_s_barrier();
        bf16x8 af[4], bfr[4];
        for (int i = 0; i < 4; i++) af[i]  = *(bf16x8*)&Ac[(wm + i * 16 + l16) * 32 + swk];
        for (int j = 0; j < 4; j++) bfr[j] = *(bf16x8*)&Bc[(wn + j * 16 + l16) * 32 + swk];
        for (int i = 0; i < 4; i++)
            for (int j = 0; j < 4; j++)
                acc[i][j] = __builtin_amdgcn_mfma_f32_16x16x32_bf16(af[i], bfr[j], acc[i][j], 0, 0, 0);
        __builtin_amdgcn_sched_barrier(0);
        __builtin_amdgcn_s_barrier();
    }

    // epilogue: bias+relu -> per-wave LDS patch (swizzled) -> coalesced stores
    ushort* patch = smem + wave * 4096;   // 64x64 bf16
    for (int j = 0; j < 4; j++) {
        const float bv = bias[n0 + wn + j * 16 + l16];
        const int colsw = (j * 16 + l16) ^ (quad * 16);
        for (int i = 0; i < 4; i++)
            for (int rr = 0; rr < 4; rr++) {
                float v = acc[i][j][rr] + bv;
                v = v > 0.f ? v : 0.f;
                patch[(i * 16 + quad * 4 + rr) * 64 + colsw] = ((ushort2*)&v)[0].y;
            }
    }
    __syncthreads();
    #pragma unroll
    for (int it = 0; it < 8; it++) {
        const int lr = it * 8 + (lane >> 3);
        const int lc = ((lane & 7) * 8) ^ (((lr >> 2) & 3) * 16);
        const bf16x8 v = *(const bf16x8*)&patch[lr * 64 + lc];
        *(bf16x8*)&Out[(size_t)(m0 + wm + lr) * 512 + n0 + wn + (((lane & 7) * 8))] = v;
    }
}

// ---------------------------------------------------------------------------
// Scores GEMM (NT) — R2-measured structure (46.8us): BK=64 single-buffer,
// 8 K-steps, __syncthreads, 32 MFMA per barrier pair, 33 KB LDS -> 4
// blocks/CU (implicit wave-overlap hides staging, m114).
// P = exp(s*scale - SHIFT) bf16 via swizzled LDS patch + column sums Lp.
// ---------------------------------------------------------------------------
__global__ __launch_bounds__(256, 4) void scores_kernel(
    const __bf16* __restrict__ Q,   // [B*S, D] bf16
    const __bf16* __restrict__ Km,  // [B*S, D] bf16
    __bf16* __restrict__ P,         // [B, S, S] bf16
    float* __restrict__ Lp)         // [QSPLIT, B, S] partial column sums
{
    __shared__ __align__(16) ushort smem[2 * 128 * 64];   // As | Bs, 32 KB
    __shared__ float stats[256];                          // Ls
    ushort* As = smem;
    ushort* Bs = smem + 128 * 64;
    const int id = blockIdx.x;            // 0..2047
    const int b = id & 7;
    const int rest = id >> 3;             // 0..255
    const int qy = rest >> 4;             // q tile 0..15
    const int m0 = qy * 128;
    const int n0 = (rest & 15) * 128;     // k tile
    const __bf16* A  = Q  + (size_t)b * Ss * Dd;
    const __bf16* Bp = Km + (size_t)b * Ss * Dd;
    __bf16* C = P + (size_t)b * Ss * Ss;

    const int tid = threadIdx.x;
    const int wave = tid >> 6, lane = tid & 63, quad = lane >> 4, l16 = lane & 15;
    const int wm = (wave >> 1) * 64, wn = (wave & 1) * 64;
    const int sw0 = ((quad)     ^ (l16 & 7)) * 8;
    const int sw1 = ((quad + 4) ^ (l16 & 7)) * 8;
    const float scale = 0.044194173824159216f; // 1/sqrt(512)
    const float SHIFT = 8.0f;

    f32x4 acc[4][4];
    f32x4 zero = {0.f, 0.f, 0.f, 0.f};
    for (int i = 0; i < 4; i++) for (int j = 0; j < 4; j++) acc[i][j] = zero;

    for (int k0 = 0; k0 < Dd; k0 += 64) {
        stage64(As, A  + (size_t)m0 * Dd + k0, Dd, wave, lane);
        stage64(Bs, Bp + (size_t)n0 * Dd + k0, Dd, wave, lane);
        __syncthreads();
        #pragma unroll
        for (int h = 0; h < 2; h++) {
            const int sw = h ? sw1 : sw0;
            bf16x8 af[4], bfr[4];
            for (int i = 0; i < 4; i++) af[i]  = *(bf16x8*)&As[(wm + i * 16 + l16) * 64 + sw];
            for (int j = 0; j < 4; j++) bfr[j] = *(bf16x8*)&Bs[(wn + j * 16 + l16) * 64 + sw];
            for (int i = 0; i < 4; i++)
                for (int j = 0; j < 4; j++)
                    acc[i][j] = __builtin_amdgcn_mfma_f32_16x16x32_bf16(af[i], bfr[j], acc[i][j], 0, 0, 0);
        }
        __syncthreads();
    }

    // ---- exp -> per-wave LDS patch (swizzled, reuses As/Bs) + column sums ----
    float* Ls = stats;                    // 256 f32
    const int half = wave >> 1;
    ushort* patch = smem + wave * 4096;   // 64x64 bf16
    float lj[4];
    for (int j = 0; j < 4; j++) {
        float l = 0.f;
        const int colsw = (j * 16 + l16) ^ (quad * 16);
        for (int i = 0; i < 4; i++)
            for (int rr = 0; rr < 4; rr++) {
                const float e = __expf(fmaf(acc[i][j][rr], scale, -SHIFT));
                const __bf16 pb = (__bf16)e;   // RNE
                patch[(i * 16 + quad * 4 + rr) * 64 + colsw] = *(const ushort*)&pb;
                l += e;
            }
        l += __shfl_xor(l, 16);
        l += __shfl_xor(l, 32);
        lj[j] = l;
    }
    if (quad == 0)
        for (int j = 0; j < 4; j++) Ls[half * 128 + wn + j * 16 + l16] = lj[j];
    __syncthreads();
    if (tid < 128) {
        const size_t o = ((size_t)qy * Bb + b) * Ss + n0 + tid;
        Lp[o] = Ls[tid] + Ls[128 + tid];
    }
    // ---- coalesced P store: 8 bf16x8 per thread ----
    #pragma unroll
    for (int it = 0; it < 8; it++) {
        const int lr = it * 8 + (lane >> 3);
        const int lc = ((lane & 7) * 8) ^ (((lr >> 2) & 3) * 16);
        const bf16x8 v = *(const bf16x8*)&patch[lr * 64 + lc];
        *(bf16x8*)&C[(size_t)(m0 + wm + lr) * Ss + n0 + wn + ((lane & 7) * 8)] = v;
    }
}

// ---------------------------------------------------------------------------
// csx_kernel: fused stats_combine + xscale.
// Grid 512 = 8 b x 64 groups of 8 e-rows. Each block recomputes the full
// Cinv[b][:] into LDS (same qy summation order -> bit-identical), then
// XC[b,e,k] = xT[b,e,k] * Cinv[b,k] for its 8 rows.
// ---------------------------------------------------------------------------
__global__ __launch_bounds__(256) void csx_kernel(const float* __restrict__ Lp,
                                                  const __bf16* __restrict__ xT,
                                                  __bf16* __restrict__ XC) {
    __shared__ float cinv[2048];
    const int b = blockIdx.x >> 6;        // 0..7
    const int g = blockIdx.x & 63;        // 0..63
    const int tid = threadIdx.x;
    const int k0 = tid * 8;
    float s[8];
    #pragma unroll
    for (int u = 0; u < 8; ++u) s[u] = 0.f;
    for (int qy = 0; qy < QSPLIT; ++qy) {
        const float* lp = Lp + ((size_t)qy * Bb + b) * Ss + k0;
        const float4 a0 = *(const float4*)lp;
        const float4 a1 = *(const float4*)(lp + 4);
        s[0] += a0.x; s[1] += a0.y; s[2] += a0.z; s[3] += a0.w;
        s[4] += a1.x; s[5] += a1.y; s[6] += a1.z; s[7] += a1.w;
    }
    #pragma unroll
    for (int u = 0; u < 8; ++u) cinv[k0 + u] = 1.0f / s[u];
    __syncthreads();
    const float4 c0 = *(const float4*)&cinv[k0];
    const float4 c1 = *(const float4*)&cinv[k0 + 4];
    #pragma unroll
    for (int r = 0; r < 8; ++r) {
        const int e = g * 8 + r;
        const size_t base = ((size_t)b * Ee + e) * Ss;
        const bf16x8 v = *(const bf16x8*)&xT[base + k0];
        bf16x8 o;
        o[0] = (__bf16)((float)v[0] * c0.x);
        o[1] = (__bf16)((float)v[1] * c0.y);
        o[2] = (__bf16)((float)v[2] * c0.z);
        o[3] = (__bf16)((float)v[3] * c0.w);
        o[4] = (__bf16)((float)v[4] * c1.x);
        o[5] = (__bf16)((float)v[5] * c1.y);
        o[6] = (__bf16)((float)v[6] * c1.z);
        o[7] = (__bf16)((float)v[7] * c1.w);
        *(bf16x8*)&XC[base + k0] = o;
    }
}

// ---------------------------------------------------------------------------
// PV GEMM (NT) — R2-measured structure (45.6us): pure GEMM Out = P @ XC + XB.
// 64x128 tile, 4 waves (wave tile 32x64), BK=64 single-buffer, __syncthreads,
// 24 KB LDS, residual fused.
// ---------------------------------------------------------------------------
__global__ __launch_bounds__(256, 4) void pv_kernel(
    const __bf16* __restrict__ P,    // [B,S,S] bf16 shifted exp scores
    const __bf16* __restrict__ XC,   // [B,E,S] bf16 x^T pre-scaled by 1/l[k]
    const __bf16* __restrict__ XB,   // [B,S,E] bf16 (residual)
    float* __restrict__ Out)         // [B,S,E] f32
{
    __shared__ __align__(16) ushort smem[64 * 64 + 128 * 64];   // As 8KB | Bs 16KB
    ushort* As = smem;
    ushort* Bs = smem + 64 * 64;
    const int id = blockIdx.x;            // 0..1023
    const int b = id & 7;
    const int rest = id >> 3;             // 0..127
    const int m0 = (rest >> 2) * 64;      // q tile (64 rows)
    const int n0 = (rest & 3) * 128;      // e tile
    const __bf16* A  = P  + (size_t)b * Ss * Ss;
    const __bf16* Bp = XC + (size_t)b * Ee * Ss;

    const int tid = threadIdx.x;
    const int wave = tid >> 6, lane = tid & 63, quad = lane >> 4, l16 = lane & 15;
    const int wm = (wave >> 1) * 32, wn = (wave & 1) * 64;
    const int sw0 = ((quad)     ^ (l16 & 7)) * 8;
    const int sw1 = ((quad + 4) ^ (l16 & 7)) * 8;

    f32x4 acc[2][4];
    f32x4 zero = {0.f, 0.f, 0.f, 0.f};
    for (int i = 0; i < 2; i++) for (int j = 0; j < 4; j++) acc[i][j] = zero;

    for (int k0 = 0; k0 < Ss; k0 += 64) {
        stage64h(As, A  + (size_t)m0 * Ss + k0, Ss, wave, lane);
        stage64 (Bs, Bp + (size_t)n0 * Ss + k0, Ss, wave, lane);
        __syncthreads();
        #pragma unroll
        for (int h = 0; h < 2; h++) {
            const int sw = h ? sw1 : sw0;
            bf16x8 af[2], bfr[4];
            for (int i = 0; i < 2; i++) af[i]  = *(bf16x8*)&As[(wm + i * 16 + l16) * 64 + sw];
            for (int j = 0; j < 4; j++) bfr[j] = *(bf16x8*)&Bs[(wn + j * 16 + l16) * 64 + sw];
            for (int i = 0; i < 2; i++)
                for (int j = 0; j < 4; j++)
                    acc[i][j] = __builtin_amdgcn_mfma_f32_16x16x32_bf16(af[i], bfr[j], acc[i][j], 0, 0, 0);
        }
        __syncthreads();
    }

    for (int i = 0; i < 2; i++) {
        for (int j = 0; j < 4; j++) {
            const int col = n0 + wn + j * 16 + l16;
            for (int rr = 0; rr < 4; rr++) {
                const int row = m0 + wm + i * 16 + quad * 4 + rr;
                const size_t idx = ((size_t)b * Ss + row) * Ee + col;
                Out[idx] = (float)XB[idx] + acc[i][j][rr];
            }
        }
    }
}

// ---------------------------------------------------------------------------
extern "C" void kernel_launch(void* const* d_in, const int* in_sizes, int n_in,
                              void* d_out, int out_size, void* d_ws, size_t ws_size,
                              hipStream_t stream) {
    const float* x  = (const float*)d_in[0];
    const float* Wq = (const float*)d_in[1];
    const float* bq = (const float*)d_in[2];
    const float* Wk = (const float*)d_in[3];
    const float* bk = (const float*)d_in[4];
    float* out = (float*)d_out;

    char* ws = (char*)d_ws;
    size_t off = 0;
    auto alloc = [&](size_t bytes) -> void* {
        void* p = ws + off;
        off += (bytes + 255) & ~(size_t)255;
        return p;
    };
    __bf16* P    = (__bf16*)alloc((size_t)Bb * Ss * Ss * 2);      // 64 MiB
    __bf16* xb   = (__bf16*)alloc((size_t)Bb * Ss * Ee * 2);
    __bf16* qb   = (__bf16*)alloc((size_t)Bb * Ss * Dd * 2);
    __bf16* kb   = (__bf16*)alloc((size_t)Bb * Ss * Dd * 2);
    __bf16* xT   = (__bf16*)alloc((size_t)Bb * Ee * Ss * 2);
    __bf16* WqT  = (__bf16*)alloc((size_t)512 * 512 * 2);
    __bf16* WkT  = (__bf16*)alloc((size_t)512 * 512 * 2);
    float*  Lp   = (float*)alloc((size_t)QSPLIT * Bb * Ss * 4);   // 1 MiB
    if (off > ws_size) return;
    __bf16* XC = qb;   // reuse: qb is dead after scores_kernel (stream-ordered)

    // xb, xT, WqT, WkT in one launch
    prep_fused<<<dim3(2048 + 512), 256, 0, stream>>>(x, Wq, Wk, xb, xT, WqT, WkT);

    // q = relu(x Wq + bq), k = relu(x Wk + bk)
    proj_kernel<<<dim3(4, 128, 2), 256, 0, stream>>>(xb, WqT, WkT, bq, bk, qb, kb);

    // P = exp(q k^T / sqrt(E) - 8) bf16 + column-sum partials
    scores_kernel<<<dim3(2048), 256, 0, stream>>>(qb, kb, P, Lp);

    // XC = x^T / l[k]   (fused normalizer combine + scale)
    csx_kernel<<<dim3(512), 256, 0, stream>>>(Lp, xT, XC);

    // out = x + P @ XC   (pure GEMM, residual fused)
    pv_kernel<<<dim3(1024), 256, 0, stream>>>(P, XC, xb, out);
}